// Round 1
// baseline (14334.042 us; speedup 1.0000x reference)
//
#include <hip/hip_runtime.h>

// Seq2SeqBridge: persistent cooperative kernel, f16 MFMA, register-resident weights.
// R1 protocol change vs previous best (4900 us):
//  1) Barrier: central per-domain atomic counter (128 serialized fetch_adds on ONE
//     LLC dword per tick) -> distributed per-WG epoch flags (16B apart). Arrival is
//     a single relaxed sc1 store; wave 0 polls all domain flags (1-2 loads/lane).
//  2) Broadcast reads: sc1 (L2-bypass) loads forced every WG to pull the full
//     hidden state from LLC every tick (~24 MB/tick). Now normal CACHED loads;
//     freshness via agent-scope acquire fence (L1+L2 invalidate) at every barrier
//     exit, so the 32 WGs/XCD share one L2 copy per tick.
// Cross-WG STORES stay sc1 (straight to LLC); the pre-arrival __syncthreads drains
// vmcnt(0), so data is LLC-visible before the flag store is issued.

typedef _Float16 f16;
typedef _Float16 hvec8 __attribute__((ext_vector_type(8)));
typedef float fvec4 __attribute__((ext_vector_type(4)));

#define WS_H0   4096
#define WS_H1   135168
#define WS_HE   266240
#define WS_DEC  397312
#define WS_Y0   17174528
// ws[0..4096): 256 WGs x 16B epoch flags (memset to 0 each launch)

__device__ __forceinline__ fvec4 mf(hvec8 a, hvec8 b, fvec4 c) {
    return __builtin_amdgcn_mfma_f32_16x16x32_f16(a, b, c, 0, 0, 0);
}

// weights: normal cached loads (read-only, converted once into registers)
__device__ __forceinline__ hvec8 ldb8(const float* p) {
    hvec8 h;
#pragma unroll
    for (int j = 0; j < 8; ++j) h[j] = (f16)p[j];
    return h;
}

// cross-WG state reads: plain cached 16B load (L1/L2); freshness guaranteed by the
// acquire fence executed at every barrier exit before any of these loads.
__device__ __forceinline__ hvec8 ldc8(const f16* p) {
    return *(const hvec8*)p;
}

// cross-WG state writes: relaxed agent-scope atomics -> global_store sc1 (to LLC)
__device__ __forceinline__ void st2(f16* p, float a, float b) {
    union { f16 h[2]; unsigned u; } x;
    x.h[0] = (f16)a; x.h[1] = (f16)b;
    __hip_atomic_store((unsigned*)p, x.u, __ATOMIC_RELAXED, __HIP_MEMORY_SCOPE_AGENT);
}

__device__ __forceinline__ float sigf(float x) { return 1.f / (1.f + __expf(-x)); }
__device__ __forceinline__ float thf(float x) {
    x = fminf(15.f, fmaxf(-15.f, x));
    float e = __expf(2.f * x);
    return (e - 1.f) / (e + 1.f);
}

// LDS layouts: RED row stride 132 (2-way bank conflicts only), RED2 stride 20
#define RED(t, m, w, n)  red[(((t)*16 + (m))*132) + ((w)*16) + (n)]
#define RED2(t, m, n)    red2[(((t)*16 + (m))*20) + (n)]

__global__ void __launch_bounds__(512, 1)
seq2seq_kernel(const float* __restrict__ enc_h, const float* __restrict__ enc_c,
               const float* __restrict__ emb_W,
               const float* __restrict__ dWih0, const float* __restrict__ dWhh0,
               const float* __restrict__ dbih0, const float* __restrict__ dbhh0,
               const float* __restrict__ dWih1, const float* __restrict__ dWhh1,
               const float* __restrict__ dbih1, const float* __restrict__ dbhh1,
               const float* __restrict__ eWih, const float* __restrict__ eWhh,
               const float* __restrict__ ebih, const float* __restrict__ ebhh,
               float* __restrict__ out, char* __restrict__ ws)
{
    const int tid  = threadIdx.x;
    const int wave = tid >> 6, lane = tid & 63;
    const int wg   = blockIdx.x;
    const int bg   = wg >> 7;        // batch group (batches 16*bg .. 16*bg+15)
    const int g    = wg & 127;       // index within group
    const int n16  = lane & 15;
    const int kq   = (lane >> 4) * 8;

    unsigned* flags  = (unsigned*)ws;          // 256 x 16B
    unsigned* myflag = flags + (size_t)wg * 4;

    f16* H0  = (f16*)(ws + WS_H0);    // [2 par][32][1024]
    f16* H1  = (f16*)(ws + WS_H1);    // [2 par][32][1024]
    f16* HE  = (f16*)(ws + WS_HE);    // [2 dir][2 par][32][512]
    f16* DEC = (f16*)(ws + WS_DEC);   // [256][32][1024]
    f16* Y0  = (f16*)(ws + WS_Y0);    // [256][32][1024]

    __shared__ float red[64 * 132];
    __shared__ float red2[64 * 20];
    __shared__ float cdec[2][8][16];
    __shared__ float cenc[8][16];
    __shared__ float pre0_l[32];
    __shared__ float bias1_l[32];
    __shared__ float biasE_l[32];

    unsigned cnt = 0;
    // barrier over flags[base .. base+64*(1+two)); every WG in a bg executes the
    // SAME barrier-call sequence, so one monotone epoch per WG serves all domains.
    auto bar = [&](int base, int two) {
        const unsigned tgt = ++cnt;
        __syncthreads();   // vmcnt(0) drain: this WG's sc1 stores are LLC-visible
        if (wave == 0) {
            if (lane == 0)
                __hip_atomic_store(myflag, tgt, __ATOMIC_RELAXED, __HIP_MEMORY_SCOPE_AGENT);
            const unsigned* p0 = flags + (size_t)(base + lane) * 4;
            const unsigned* p1 = p0 + 64 * 4;
            for (;;) {
                unsigned a = __hip_atomic_load(p0, __ATOMIC_RELAXED, __HIP_MEMORY_SCOPE_AGENT);
                if (two) {
                    unsigned b = __hip_atomic_load(p1, __ATOMIC_RELAXED, __HIP_MEMORY_SCOPE_AGENT);
                    a = (a < b) ? a : b;
                }
                if (__all((int)(a >= tgt))) break;
                __builtin_amdgcn_s_sleep(1);
            }
        }
        __syncthreads();
        // invalidate L1 + this XCD's L2: all stale copies of cross-tick state die
        // here; subsequent cached loads refill from the (fresh) LLC.
        __builtin_amdgcn_fence(__ATOMIC_ACQUIRE, "agent");
    };

    // ---------------- P0: decoder weight fragments -> registers -----------------
    const int u0 = g * 8;
    hvec8 bL0[2][4], bL1[2][8];
    {
        const int gate = n16 >> 2, uu = n16 & 3;
#pragma unroll
        for (int t = 0; t < 2; ++t) {
            const int r = gate * 1024 + u0 + t * 4 + uu;
#pragma unroll
            for (int s = 0; s < 4; ++s)
                bL0[t][s] = ldb8(dWhh0 + (size_t)r * 1024 + wave * 128 + s * 32 + kq);
#pragma unroll
            for (int s = 0; s < 8; ++s) {
                const int k1 = wave * 256 + s * 32;
                bL1[t][s] = (k1 < 1024)
                    ? ldb8(dWih1 + (size_t)r * 1024 + k1 + kq)
                    : ldb8(dWhh1 + (size_t)r * 1024 + (k1 - 1024) + kq);
            }
        }
    }
    // ---------------- P0: state init + pre0/biases -------------------------------
    if (tid < 128) {
        const int which = tid >> 6, q = tid & 63, j = q >> 4, m = q & 15;
        const int b = bg * 16 + m, u = u0 + 2 * j;
        const float* src_c = enc_c + (size_t)(which * 32 + b) * 1024 + u;
        const float* src_h = enc_h + (size_t)(which * 32 + b) * 1024 + u;
        cdec[which][2 * j][m]     = src_c[0];
        cdec[which][2 * j + 1][m] = src_c[1];
        f16* dst = which ? H1 : H0;
        st2(dst + (size_t)(32 + b) * 1024 + u, src_h[0], src_h[1]);  // parity 1
    }
    if (tid < 32) {
        const int t = tid >> 4, nn = tid & 15;
        const int r = (nn >> 2) * 1024 + u0 + t * 4 + (nn & 3);
        const float* x0 = emb_W + 512;          // emb_W[BOS=1]
        float s = dbih0[r] + dbhh0[r];
        const float* wr = dWih0 + (size_t)r * 512;
        for (int k = 0; k < 512; ++k) s += wr[k] * x0[k];
        pre0_l[tid]  = s;
        bias1_l[tid] = dbih1[r] + dbhh1[r];
    }
    bar(bg * 128, 1);

    // ---------------- decoder: 257 pipelined ticks -------------------------------
    for (int tau = 0; tau <= 256; ++tau) {
        const int prd = (tau + 1) & 1;   // h0 read parity; h1 write parity
        const int pwr = tau & 1;         // h0 write parity; h1 read parity
        fvec4 acc[4];
#pragma unroll
        for (int i = 0; i < 4; ++i) acc[i] = 0;
        const int m = n16;
        if (tau < 256) {
            const f16* a0 = H0 + (size_t)(prd * 32 + bg * 16 + m) * 1024 + wave * 128 + kq;
#pragma unroll
            for (int s = 0; s < 4; ++s) {
                hvec8 a = ldc8(a0 + s * 32);
                acc[0] = mf(a, bL0[0][s], acc[0]);
                acc[1] = mf(a, bL0[1][s], acc[1]);
            }
        }
        if (tau >= 1) {
            const f16* a1 = (wave < 4)
                ? H0 + (size_t)(prd * 32 + bg * 16 + m) * 1024 + wave * 256 + kq
                : H1 + (size_t)(pwr * 32 + bg * 16 + m) * 1024 + (wave - 4) * 256 + kq;
#pragma unroll
            for (int s = 0; s < 8; ++s) {
                hvec8 a = ldc8(a1 + s * 32);
                acc[2] = mf(a, bL1[0][s], acc[2]);
                acc[3] = mf(a, bL1[1][s], acc[3]);
            }
        }
        {
            const int mg = lane >> 4;
#pragma unroll
            for (int t = 0; t < 4; ++t)
#pragma unroll
                for (int r = 0; r < 4; ++r)
                    RED(t, mg * 4 + r, wave, n16) = acc[t][r];
        }
        __syncthreads();
        for (int it = tid; it < 1024; it += 512) {
            const int t = it >> 8, mm = it & 15, nn = (it >> 4) & 15;
            const float* p = &RED(t, mm, 0, nn);
            RED2(t, mm, nn) = ((p[0] + p[16]) + (p[32] + p[48]))
                            + ((p[64] + p[80]) + (p[96] + p[112]));
        }
        __syncthreads();
        if (tid < 64 && tau < 256) {                       // L0 pointwise (wave 0)
            const int j = tid >> 4, m2 = tid & 15, t = j >> 1;
            float hh[2];
#pragma unroll
            for (int e = 0; e < 2; ++e) {
                const int uu = 2 * j + e, ul = uu & 3;
                const float gi = RED2(t, m2, ul)      + pre0_l[t * 16 + ul];
                const float gf = RED2(t, m2, 4 + ul)  + pre0_l[t * 16 + 4 + ul];
                const float gg = RED2(t, m2, 8 + ul)  + pre0_l[t * 16 + 8 + ul];
                const float go = RED2(t, m2, 12 + ul) + pre0_l[t * 16 + 12 + ul];
                float c = cdec[0][uu][m2];
                c = sigf(gf) * c + sigf(gi) * thf(gg);
                hh[e] = sigf(go) * thf(c);
                cdec[0][uu][m2] = c;
            }
            st2(H0 + (size_t)(pwr * 32 + bg * 16 + m2) * 1024 + u0 + 2 * j, hh[0], hh[1]);
        }
        if (tid >= 64 && tid < 128 && tau >= 1) {          // L1 pointwise (wave 1)
            const int q = tid - 64;
            const int j = q >> 4, m2 = q & 15, t = j >> 1;
            float hh[2];
#pragma unroll
            for (int e = 0; e < 2; ++e) {
                const int uu = 2 * j + e, ul = uu & 3;
                const float gi = RED2(2 + t, m2, ul)      + bias1_l[t * 16 + ul];
                const float gf = RED2(2 + t, m2, 4 + ul)  + bias1_l[t * 16 + 4 + ul];
                const float gg = RED2(2 + t, m2, 8 + ul)  + bias1_l[t * 16 + 8 + ul];
                const float go = RED2(2 + t, m2, 12 + ul) + bias1_l[t * 16 + 12 + ul];
                float c = cdec[1][uu][m2];
                c = sigf(gf) * c + sigf(gi) * thf(gg);
                hh[e] = sigf(go) * thf(c);
                cdec[1][uu][m2] = c;
            }
            const int b = bg * 16 + m2, u = u0 + 2 * j;
            st2(H1 + (size_t)(prd * 32 + b) * 1024 + u, hh[0], hh[1]);
            st2(DEC + ((size_t)(tau - 1) * 32 + b) * 1024 + u, hh[0], hh[1]);
        }
        bar(bg * 128, 1);
    }

    // ---------------- encoder: 2 layers x 256 ticks, fwd/bwd in own domains ------
    const int dir = g >> 6;
    const int ge  = g & 63;
    const int ue0 = ge * 8;
    const int dbase = bg * 128 + dir * 64;
    for (int l = 0; l < 2; ++l) {
        hvec8 bE[2][6];
        {
            const int gate = n16 >> 2, uu = n16 & 3;
            const float* Wih = eWih + (size_t)(l * 2 + dir) * 2048 * 1024;
            const float* Whh = eWhh + (size_t)(l * 2 + dir) * 2048 * 512;
#pragma unroll
            for (int t = 0; t < 2; ++t) {
                const int r = gate * 512 + ue0 + t * 4 + uu;
#pragma unroll
                for (int s = 0; s < 6; ++s) {
                    const int kb = wave * 192 + s * 32;
                    bE[t][s] = (kb < 1024)
                        ? ldb8(Wih + (size_t)r * 1024 + kb + kq)
                        : ldb8(Whh + (size_t)r * 512 + (kb - 1024) + kq);
                }
            }
        }
        if (tid < 32) {
            const int t = tid >> 4, nn = tid & 15;
            const int r = (nn >> 2) * 512 + ue0 + t * 4 + (nn & 3);
            biasE_l[tid] = ebih[(size_t)(l * 2 + dir) * 2048 + r]
                         + ebhh[(size_t)(l * 2 + dir) * 2048 + r];
        }
        if (tid < 64) {
            const int j = tid >> 4, m = tid & 15;
            cenc[2 * j][m] = 0.f;
            cenc[2 * j + 1][m] = 0.f;
            st2(HE + (size_t)((dir * 2 + 1) * 32 + bg * 16 + m) * 512 + ue0 + 2 * j, 0.f, 0.f);
        }
        bar(dbase, 0);
        const f16* yprev = (l == 0) ? DEC : Y0;
        for (int tau = 0; tau < 256; ++tau) {
            const int t = dir ? (255 - tau) : tau;
            const int prd = (tau + 1) & 1, pwr = tau & 1;
            fvec4 acc2[2];
            acc2[0] = 0; acc2[1] = 0;
            const int m = n16, b = bg * 16 + m;
#pragma unroll
            for (int s = 0; s < 6; ++s) {
                const int kb = wave * 192 + s * 32;
                const f16* p = (kb < 1024)
                    ? yprev + ((size_t)t * 32 + b) * 1024 + kb + kq
                    : HE + (size_t)((dir * 2 + prd) * 32 + b) * 512 + (kb - 1024) + kq;
                hvec8 a = ldc8(p);
                acc2[0] = mf(a, bE[0][s], acc2[0]);
                acc2[1] = mf(a, bE[1][s], acc2[1]);
            }
            const int mg = lane >> 4;
#pragma unroll
            for (int tt = 0; tt < 2; ++tt)
#pragma unroll
                for (int r = 0; r < 4; ++r)
                    RED(tt, mg * 4 + r, wave, n16) = acc2[tt][r];
            __syncthreads();
            {
                const int t2 = tid >> 8, mm = tid & 15, nn = (tid >> 4) & 15;
                const float* p = &RED(t2, mm, 0, nn);
                RED2(t2, mm, nn) = ((p[0] + p[16]) + (p[32] + p[48]))
                                 + ((p[64] + p[80]) + (p[96] + p[112]));
            }
            __syncthreads();
            if (tid < 64) {
                const int j = tid >> 4, m2 = tid & 15, tt = j >> 1;
                float hh[2], cc[2];
#pragma unroll
                for (int e = 0; e < 2; ++e) {
                    const int uu = 2 * j + e, ul = uu & 3;
                    const float gi = RED2(tt, m2, ul)      + biasE_l[tt * 16 + ul];
                    const float gf = RED2(tt, m2, 4 + ul)  + biasE_l[tt * 16 + 4 + ul];
                    const float gg = RED2(tt, m2, 8 + ul)  + biasE_l[tt * 16 + 8 + ul];
                    const float go = RED2(tt, m2, 12 + ul) + biasE_l[tt * 16 + 12 + ul];
                    float c = cenc[uu][m2];
                    c = sigf(gf) * c + sigf(gi) * thf(gg);
                    hh[e] = sigf(go) * thf(c);
                    cc[e] = c;
                    cenc[uu][m2] = c;
                }
                const int b2 = bg * 16 + m2, u = ue0 + 2 * j;
                st2(HE + (size_t)((dir * 2 + pwr) * 32 + b2) * 512 + u, hh[0], hh[1]);
                if (l == 0) {
                    st2(Y0 + ((size_t)t * 32 + b2) * 1024 + dir * 512 + u, hh[0], hh[1]);
                } else {
                    float* o = out + ((size_t)b2 * 256 + t) * 1024 + dir * 512 + u;
                    o[0] = hh[0]; o[1] = hh[1];
                    if (tau == 255) {   // final states -> dec_h / dec_c
                        const int col = dir * 512 + u;
                        float* oh = out + 8388608 + (size_t)b2 * 1024 + col;
                        float* oc = out + 8454144 + (size_t)b2 * 1024 + col;
                        oh[0] = hh[0]; oh[1] = hh[1];
                        oh[32768] = hh[0]; oh[32769] = hh[1];
                        oc[0] = cc[0]; oc[1] = cc[1];
                        oc[32768] = cc[0]; oc[32769] = cc[1];
                    }
                }
            }
            bar(dbase, 0);
        }
        if (l == 0) bar(bg * 128, 1);  // Y0 (both dirs) complete
    }
}

extern "C" void kernel_launch(void* const* d_in, const int* in_sizes, int n_in,
                              void* d_out, int out_size, void* d_ws, size_t ws_size,
                              hipStream_t stream) {
    (void)in_sizes; (void)n_in; (void)out_size; (void)ws_size;
    const float* enc_h = (const float*)d_in[1];
    const float* enc_c = (const float*)d_in[2];
    const float* emb_W = (const float*)d_in[4];
    const float* dWih0 = (const float*)d_in[5];
    const float* dWhh0 = (const float*)d_in[6];
    const float* dbih0 = (const float*)d_in[7];
    const float* dbhh0 = (const float*)d_in[8];
    const float* dWih1 = (const float*)d_in[9];
    const float* dWhh1 = (const float*)d_in[10];
    const float* dbih1 = (const float*)d_in[11];
    const float* dbhh1 = (const float*)d_in[12];
    const float* eWih  = (const float*)d_in[13];
    const float* eWhh  = (const float*)d_in[14];
    const float* ebih  = (const float*)d_in[15];
    const float* ebhh  = (const float*)d_in[16];
    float* outp = (float*)d_out;
    char* ws = (char*)d_ws;

    // zero the epoch flags (ws is re-poisoned before every launch)
    hipMemsetAsync(d_ws, 0, 4096, stream);

    void* args[] = {&enc_h, &enc_c, &emb_W, &dWih0, &dWhh0, &dbih0, &dbhh0,
                    &dWih1, &dWhh1, &dbih1, &dbhh1, &eWih, &eWhh, &ebih, &ebhh,
                    &outp, &ws};
    hipLaunchCooperativeKernel((const void*)seq2seq_kernel, dim3(256), dim3(512),
                               args, 0, stream);
}

// Round 2
// 3795.424 us; speedup vs baseline: 3.7767x; 3.7767x over previous
//
#include <hip/hip_runtime.h>

// Seq2SeqBridge: persistent cooperative kernel, f16 MFMA, register-resident weights.
// R2 vs R0 (4900 us): data protocol IDENTICAL to R0 (all cross-WG state via sc1 /
// agent-scope relaxed atomics, NO cache fences -- R1's per-tick L2 invalidate was a
// 3x regression). Two isolated changes:
//  1) Barrier: central per-domain atomic counter (128 serialized fetch_adds on one
//     LLC dword per tick) -> distributed per-WG epoch flags (16B apart). Arrival is
//     one relaxed sc1 store; wave 0 polls all domain flags in parallel (__all).
//  2) Cross-WG state reads: two 8B atomic loads -> one global_load_dwordx4 sc1
//     (agent scope = sc1 on CDNA4), all fragments issued back-to-back, then a
//     single s_waitcnt vmcnt(0) + sched_barrier(0) before the MFMA cluster.

typedef _Float16 f16;
typedef _Float16 hvec8 __attribute__((ext_vector_type(8)));
typedef float fvec4 __attribute__((ext_vector_type(4)));

#define WS_H0   4096
#define WS_H1   135168
#define WS_HE   266240
#define WS_DEC  397312
#define WS_Y0   17174528
// ws[0..4096): 256 WGs x 16B epoch flags (memset to 0 each launch)

__device__ __forceinline__ fvec4 mf(hvec8 a, hvec8 b, fvec4 c) {
    return __builtin_amdgcn_mfma_f32_16x16x32_f16(a, b, c, 0, 0, 0);
}

// weights: normal cached loads (read-only, converted once into registers)
__device__ __forceinline__ hvec8 ldb8(const float* p) {
    hvec8 h;
#pragma unroll
    for (int j = 0; j < 8; ++j) h[j] = (f16)p[j];
    return h;
}

// cross-WG state reads: one 16B load at agent scope (sc1 -> LLC, bypasses stale
// L1/L2). NO waitcnt here -- caller batches loads then waits once (rule: inline-asm
// loads are invisible to the compiler's waitcnt insertion).
__device__ __forceinline__ hvec8 lda8(const f16* p) {
    hvec8 v;
    asm volatile("global_load_dwordx4 %0, %1, off sc1" : "=v"(v) : "v"(p));
    return v;
}
__device__ __forceinline__ void vm_wait() {
    asm volatile("s_waitcnt vmcnt(0)" ::: "memory");
    __builtin_amdgcn_sched_barrier(0);
}

// cross-WG state writes: relaxed agent-scope atomics -> global_store sc1 (to LLC)
__device__ __forceinline__ void st2(f16* p, float a, float b) {
    union { f16 h[2]; unsigned u; } x;
    x.h[0] = (f16)a; x.h[1] = (f16)b;
    __hip_atomic_store((unsigned*)p, x.u, __ATOMIC_RELAXED, __HIP_MEMORY_SCOPE_AGENT);
}

__device__ __forceinline__ float sigf(float x) { return 1.f / (1.f + __expf(-x)); }
__device__ __forceinline__ float thf(float x) {
    x = fminf(15.f, fmaxf(-15.f, x));
    float e = __expf(2.f * x);
    return (e - 1.f) / (e + 1.f);
}

// LDS layouts: RED row stride 132 (2-way bank conflicts only), RED2 stride 20
#define RED(t, m, w, n)  red[(((t)*16 + (m))*132) + ((w)*16) + (n)]
#define RED2(t, m, n)    red2[(((t)*16 + (m))*20) + (n)]

__global__ void __launch_bounds__(512, 1)
seq2seq_kernel(const float* __restrict__ enc_h, const float* __restrict__ enc_c,
               const float* __restrict__ emb_W,
               const float* __restrict__ dWih0, const float* __restrict__ dWhh0,
               const float* __restrict__ dbih0, const float* __restrict__ dbhh0,
               const float* __restrict__ dWih1, const float* __restrict__ dWhh1,
               const float* __restrict__ dbih1, const float* __restrict__ dbhh1,
               const float* __restrict__ eWih, const float* __restrict__ eWhh,
               const float* __restrict__ ebih, const float* __restrict__ ebhh,
               float* __restrict__ out, char* __restrict__ ws)
{
    const int tid  = threadIdx.x;
    const int wave = tid >> 6, lane = tid & 63;
    const int wg   = blockIdx.x;
    const int bg   = wg >> 7;        // batch group (batches 16*bg .. 16*bg+15)
    const int g    = wg & 127;       // index within group
    const int n16  = lane & 15;
    const int kq   = (lane >> 4) * 8;

    unsigned* flags  = (unsigned*)ws;          // 256 x 16B
    unsigned* myflag = flags + (size_t)wg * 4;

    f16* H0  = (f16*)(ws + WS_H0);    // [2 par][32][1024]
    f16* H1  = (f16*)(ws + WS_H1);    // [2 par][32][1024]
    f16* HE  = (f16*)(ws + WS_HE);    // [2 dir][2 par][32][512]
    f16* DEC = (f16*)(ws + WS_DEC);   // [256][32][1024]
    f16* Y0  = (f16*)(ws + WS_Y0);    // [256][32][1024]

    __shared__ float red[64 * 132];
    __shared__ float red2[64 * 20];
    __shared__ float cdec[2][8][16];
    __shared__ float cenc[8][16];
    __shared__ float pre0_l[32];
    __shared__ float bias1_l[32];
    __shared__ float biasE_l[32];

    unsigned cnt = 0;
    // barrier over flags[base .. base+64*(1+two)); every WG in a bg executes the
    // SAME barrier-call sequence, so one monotone epoch per WG serves all domains.
    auto bar = [&](int base, int two) {
        const unsigned tgt = ++cnt;
        __syncthreads();   // vmcnt(0) drain: this WG's sc1 stores are LLC-visible
        if (wave == 0) {
            if (lane == 0)
                __hip_atomic_store(myflag, tgt, __ATOMIC_RELAXED, __HIP_MEMORY_SCOPE_AGENT);
            const unsigned* p0 = flags + (size_t)(base + lane) * 4;
            const unsigned* p1 = p0 + 64 * 4;
            for (;;) {
                unsigned a = __hip_atomic_load(p0, __ATOMIC_RELAXED, __HIP_MEMORY_SCOPE_AGENT);
                if (two) {
                    unsigned b = __hip_atomic_load(p1, __ATOMIC_RELAXED, __HIP_MEMORY_SCOPE_AGENT);
                    a = (a < b) ? a : b;
                }
                if (__all((int)(a >= tgt))) break;
                __builtin_amdgcn_s_sleep(2);
            }
        }
        __syncthreads();
    };

    // ---------------- P0: decoder weight fragments -> registers -----------------
    const int u0 = g * 8;
    hvec8 bL0[2][4], bL1[2][8];
    {
        const int gate = n16 >> 2, uu = n16 & 3;
#pragma unroll
        for (int t = 0; t < 2; ++t) {
            const int r = gate * 1024 + u0 + t * 4 + uu;
#pragma unroll
            for (int s = 0; s < 4; ++s)
                bL0[t][s] = ldb8(dWhh0 + (size_t)r * 1024 + wave * 128 + s * 32 + kq);
#pragma unroll
            for (int s = 0; s < 8; ++s) {
                const int k1 = wave * 256 + s * 32;
                bL1[t][s] = (k1 < 1024)
                    ? ldb8(dWih1 + (size_t)r * 1024 + k1 + kq)
                    : ldb8(dWhh1 + (size_t)r * 1024 + (k1 - 1024) + kq);
            }
        }
    }
    // ---------------- P0: state init + pre0/biases -------------------------------
    if (tid < 128) {
        const int which = tid >> 6, q = tid & 63, j = q >> 4, m = q & 15;
        const int b = bg * 16 + m, u = u0 + 2 * j;
        const float* src_c = enc_c + (size_t)(which * 32 + b) * 1024 + u;
        const float* src_h = enc_h + (size_t)(which * 32 + b) * 1024 + u;
        cdec[which][2 * j][m]     = src_c[0];
        cdec[which][2 * j + 1][m] = src_c[1];
        f16* dst = which ? H1 : H0;
        st2(dst + (size_t)(32 + b) * 1024 + u, src_h[0], src_h[1]);  // parity 1
    }
    if (tid < 32) {
        const int t = tid >> 4, nn = tid & 15;
        const int r = (nn >> 2) * 1024 + u0 + t * 4 + (nn & 3);
        const float* x0 = emb_W + 512;          // emb_W[BOS=1]
        float s = dbih0[r] + dbhh0[r];
        const float* wr = dWih0 + (size_t)r * 512;
        for (int k = 0; k < 512; ++k) s += wr[k] * x0[k];
        pre0_l[tid]  = s;
        bias1_l[tid] = dbih1[r] + dbhh1[r];
    }
    bar(bg * 128, 1);

    // ---------------- decoder: 257 pipelined ticks -------------------------------
    for (int tau = 0; tau <= 256; ++tau) {
        const int prd = (tau + 1) & 1;   // h0 read parity; h1 write parity
        const int pwr = tau & 1;         // h0 write parity; h1 read parity
        fvec4 acc[4];
#pragma unroll
        for (int i = 0; i < 4; ++i) acc[i] = 0;
        const int m = n16;
        // ---- batch-issue all fragment loads, then one wait, then MFMA cluster ----
        hvec8 a0f[4], a1f[8];
        if (tau < 256) {
            const f16* a0 = H0 + (size_t)(prd * 32 + bg * 16 + m) * 1024 + wave * 128 + kq;
#pragma unroll
            for (int s = 0; s < 4; ++s) a0f[s] = lda8(a0 + s * 32);
        }
        if (tau >= 1) {
            const f16* a1 = (wave < 4)
                ? H0 + (size_t)(prd * 32 + bg * 16 + m) * 1024 + wave * 256 + kq
                : H1 + (size_t)(pwr * 32 + bg * 16 + m) * 1024 + (wave - 4) * 256 + kq;
#pragma unroll
            for (int s = 0; s < 8; ++s) a1f[s] = lda8(a1 + s * 32);
        }
        vm_wait();
        if (tau < 256) {
#pragma unroll
            for (int s = 0; s < 4; ++s) {
                acc[0] = mf(a0f[s], bL0[0][s], acc[0]);
                acc[1] = mf(a0f[s], bL0[1][s], acc[1]);
            }
        }
        if (tau >= 1) {
#pragma unroll
            for (int s = 0; s < 8; ++s) {
                acc[2] = mf(a1f[s], bL1[0][s], acc[2]);
                acc[3] = mf(a1f[s], bL1[1][s], acc[3]);
            }
        }
        {
            const int mg = lane >> 4;
#pragma unroll
            for (int t = 0; t < 4; ++t)
#pragma unroll
                for (int r = 0; r < 4; ++r)
                    RED(t, mg * 4 + r, wave, n16) = acc[t][r];
        }
        __syncthreads();
        for (int it = tid; it < 1024; it += 512) {
            const int t = it >> 8, mm = it & 15, nn = (it >> 4) & 15;
            const float* p = &RED(t, mm, 0, nn);
            RED2(t, mm, nn) = ((p[0] + p[16]) + (p[32] + p[48]))
                            + ((p[64] + p[80]) + (p[96] + p[112]));
        }
        __syncthreads();
        if (tid < 64 && tau < 256) {                       // L0 pointwise (wave 0)
            const int j = tid >> 4, m2 = tid & 15, t = j >> 1;
            float hh[2];
#pragma unroll
            for (int e = 0; e < 2; ++e) {
                const int uu = 2 * j + e, ul = uu & 3;
                const float gi = RED2(t, m2, ul)      + pre0_l[t * 16 + ul];
                const float gf = RED2(t, m2, 4 + ul)  + pre0_l[t * 16 + 4 + ul];
                const float gg = RED2(t, m2, 8 + ul)  + pre0_l[t * 16 + 8 + ul];
                const float go = RED2(t, m2, 12 + ul) + pre0_l[t * 16 + 12 + ul];
                float c = cdec[0][uu][m2];
                c = sigf(gf) * c + sigf(gi) * thf(gg);
                hh[e] = sigf(go) * thf(c);
                cdec[0][uu][m2] = c;
            }
            st2(H0 + (size_t)(pwr * 32 + bg * 16 + m2) * 1024 + u0 + 2 * j, hh[0], hh[1]);
        }
        if (tid >= 64 && tid < 128 && tau >= 1) {          // L1 pointwise (wave 1)
            const int q = tid - 64;
            const int j = q >> 4, m2 = q & 15, t = j >> 1;
            float hh[2];
#pragma unroll
            for (int e = 0; e < 2; ++e) {
                const int uu = 2 * j + e, ul = uu & 3;
                const float gi = RED2(2 + t, m2, ul)      + bias1_l[t * 16 + ul];
                const float gf = RED2(2 + t, m2, 4 + ul)  + bias1_l[t * 16 + 4 + ul];
                const float gg = RED2(2 + t, m2, 8 + ul)  + bias1_l[t * 16 + 8 + ul];
                const float go = RED2(2 + t, m2, 12 + ul) + bias1_l[t * 16 + 12 + ul];
                float c = cdec[1][uu][m2];
                c = sigf(gf) * c + sigf(gi) * thf(gg);
                hh[e] = sigf(go) * thf(c);
                cdec[1][uu][m2] = c;
            }
            const int b = bg * 16 + m2, u = u0 + 2 * j;
            st2(H1 + (size_t)(prd * 32 + b) * 1024 + u, hh[0], hh[1]);
            st2(DEC + ((size_t)(tau - 1) * 32 + b) * 1024 + u, hh[0], hh[1]);
        }
        bar(bg * 128, 1);
    }

    // ---------------- encoder: 2 layers x 256 ticks, fwd/bwd in own domains ------
    const int dir = g >> 6;
    const int ge  = g & 63;
    const int ue0 = ge * 8;
    const int dbase = bg * 128 + dir * 64;
    for (int l = 0; l < 2; ++l) {
        hvec8 bE[2][6];
        {
            const int gate = n16 >> 2, uu = n16 & 3;
            const float* Wih = eWih + (size_t)(l * 2 + dir) * 2048 * 1024;
            const float* Whh = eWhh + (size_t)(l * 2 + dir) * 2048 * 512;
#pragma unroll
            for (int t = 0; t < 2; ++t) {
                const int r = gate * 512 + ue0 + t * 4 + uu;
#pragma unroll
                for (int s = 0; s < 6; ++s) {
                    const int kb = wave * 192 + s * 32;
                    bE[t][s] = (kb < 1024)
                        ? ldb8(Wih + (size_t)r * 1024 + kb + kq)
                        : ldb8(Whh + (size_t)r * 512 + (kb - 1024) + kq);
                }
            }
        }
        if (tid < 32) {
            const int t = tid >> 4, nn = tid & 15;
            const int r = (nn >> 2) * 512 + ue0 + t * 4 + (nn & 3);
            biasE_l[tid] = ebih[(size_t)(l * 2 + dir) * 2048 + r]
                         + ebhh[(size_t)(l * 2 + dir) * 2048 + r];
        }
        if (tid < 64) {
            const int j = tid >> 4, m = tid & 15;
            cenc[2 * j][m] = 0.f;
            cenc[2 * j + 1][m] = 0.f;
            st2(HE + (size_t)((dir * 2 + 1) * 32 + bg * 16 + m) * 512 + ue0 + 2 * j, 0.f, 0.f);
        }
        bar(dbase, 0);
        const f16* yprev = (l == 0) ? DEC : Y0;
        for (int tau = 0; tau < 256; ++tau) {
            const int t = dir ? (255 - tau) : tau;
            const int prd = (tau + 1) & 1, pwr = tau & 1;
            fvec4 acc2[2];
            acc2[0] = 0; acc2[1] = 0;
            const int m = n16, b = bg * 16 + m;
            hvec8 aef[6];
#pragma unroll
            for (int s = 0; s < 6; ++s) {
                const int kb = wave * 192 + s * 32;
                const f16* p = (kb < 1024)
                    ? yprev + ((size_t)t * 32 + b) * 1024 + kb + kq
                    : HE + (size_t)((dir * 2 + prd) * 32 + b) * 512 + (kb - 1024) + kq;
                aef[s] = lda8(p);
            }
            vm_wait();
#pragma unroll
            for (int s = 0; s < 6; ++s) {
                acc2[0] = mf(aef[s], bE[0][s], acc2[0]);
                acc2[1] = mf(aef[s], bE[1][s], acc2[1]);
            }
            const int mg = lane >> 4;
#pragma unroll
            for (int tt = 0; tt < 2; ++tt)
#pragma unroll
                for (int r = 0; r < 4; ++r)
                    RED(tt, mg * 4 + r, wave, n16) = acc2[tt][r];
            __syncthreads();
            {
                const int t2 = tid >> 8, mm = tid & 15, nn = (tid >> 4) & 15;
                const float* p = &RED(t2, mm, 0, nn);
                RED2(t2, mm, nn) = ((p[0] + p[16]) + (p[32] + p[48]))
                                 + ((p[64] + p[80]) + (p[96] + p[112]));
            }
            __syncthreads();
            if (tid < 64) {
                const int j = tid >> 4, m2 = tid & 15, tt = j >> 1;
                float hh[2], cc[2];
#pragma unroll
                for (int e = 0; e < 2; ++e) {
                    const int uu = 2 * j + e, ul = uu & 3;
                    const float gi = RED2(tt, m2, ul)      + biasE_l[tt * 16 + ul];
                    const float gf = RED2(tt, m2, 4 + ul)  + biasE_l[tt * 16 + 4 + ul];
                    const float gg = RED2(tt, m2, 8 + ul)  + biasE_l[tt * 16 + 8 + ul];
                    const float go = RED2(tt, m2, 12 + ul) + biasE_l[tt * 16 + 12 + ul];
                    float c = cenc[uu][m2];
                    c = sigf(gf) * c + sigf(gi) * thf(gg);
                    hh[e] = sigf(go) * thf(c);
                    cc[e] = c;
                    cenc[uu][m2] = c;
                }
                const int b2 = bg * 16 + m2, u = ue0 + 2 * j;
                st2(HE + (size_t)((dir * 2 + pwr) * 32 + b2) * 512 + u, hh[0], hh[1]);
                if (l == 0) {
                    st2(Y0 + ((size_t)t * 32 + b2) * 1024 + dir * 512 + u, hh[0], hh[1]);
                } else {
                    float* o = out + ((size_t)b2 * 256 + t) * 1024 + dir * 512 + u;
                    o[0] = hh[0]; o[1] = hh[1];
                    if (tau == 255) {   // final states -> dec_h / dec_c
                        const int col = dir * 512 + u;
                        float* oh = out + 8388608 + (size_t)b2 * 1024 + col;
                        float* oc = out + 8454144 + (size_t)b2 * 1024 + col;
                        oh[0] = hh[0]; oh[1] = hh[1];
                        oh[32768] = hh[0]; oh[32769] = hh[1];
                        oc[0] = cc[0]; oc[1] = cc[1];
                        oc[32768] = cc[0]; oc[32769] = cc[1];
                    }
                }
            }
            bar(dbase, 0);
        }
        if (l == 0) bar(bg * 128, 1);  // Y0 (both dirs) complete
    }
}

extern "C" void kernel_launch(void* const* d_in, const int* in_sizes, int n_in,
                              void* d_out, int out_size, void* d_ws, size_t ws_size,
                              hipStream_t stream) {
    (void)in_sizes; (void)n_in; (void)out_size; (void)ws_size;
    const float* enc_h = (const float*)d_in[1];
    const float* enc_c = (const float*)d_in[2];
    const float* emb_W = (const float*)d_in[4];
    const float* dWih0 = (const float*)d_in[5];
    const float* dWhh0 = (const float*)d_in[6];
    const float* dbih0 = (const float*)d_in[7];
    const float* dbhh0 = (const float*)d_in[8];
    const float* dWih1 = (const float*)d_in[9];
    const float* dWhh1 = (const float*)d_in[10];
    const float* dbih1 = (const float*)d_in[11];
    const float* dbhh1 = (const float*)d_in[12];
    const float* eWih  = (const float*)d_in[13];
    const float* eWhh  = (const float*)d_in[14];
    const float* ebih  = (const float*)d_in[15];
    const float* ebhh  = (const float*)d_in[16];
    float* outp = (float*)d_out;
    char* ws = (char*)d_ws;

    // zero the epoch flags (ws is re-poisoned before every launch)
    hipMemsetAsync(d_ws, 0, 4096, stream);

    void* args[] = {&enc_h, &enc_c, &emb_W, &dWih0, &dWhh0, &dbih0, &dbhh0,
                    &dWih1, &dWhh1, &dbih1, &dbhh1, &eWih, &eWhh, &ebih, &ebhh,
                    &outp, &ws};
    hipLaunchCooperativeKernel((const void*)seq2seq_kernel, dim3(256), dim3(512),
                               args, 0, stream);
}

// Round 3
// 3790.842 us; speedup vs baseline: 3.7812x; 1.0012x over previous
//
#include <hip/hip_runtime.h>

// Seq2SeqBridge: persistent cooperative kernel, f16 MFMA, register-resident weights.
// R3 vs R2 (3700 us): data protocol unchanged (sc1 agent-scope everywhere, no cache
// fences). Changes:
//  1) Encoder U=8 -> U=16: 32 WGs per (bg,dir) domain (was 64). Halves the
//     per-tick LLC broadcast (each WG reads its full 48KB k-slice regardless of U;
//     fewer WGs = fewer redundant reads). B-frags 24 hvec8 = 96 VGPR, fits.
//     WGs 128..255 exit after a one-time grid barrier at decoder end.
//  2) Encoder y-prefetch: DEC/Y0 reads (2/3 of per-tick bytes) have a known
//     schedule -> prefetch y[t+1] into registers during tick t; only the recurrent
//     HE load (16KB/WG) remains on the post-barrier critical path.
//  3) Fold RED2 reduce pass into the pointwise threads (same 8-partial sum tree,
//     bit-exact) -> one fewer __syncthreads + LDS pass per tick.
//  4) Poll loops drop s_sleep -> tighter barrier detect.

typedef _Float16 f16;
typedef _Float16 hvec8 __attribute__((ext_vector_type(8)));
typedef float fvec4 __attribute__((ext_vector_type(4)));

#define WS_H0   4096
#define WS_H1   135168
#define WS_HE   266240
#define WS_DEC  397312
#define WS_Y0   17174528
// ws[0..4096): 256 WGs x 16B epoch flags (memset to 0 each launch)

__device__ __forceinline__ fvec4 mf(hvec8 a, hvec8 b, fvec4 c) {
    return __builtin_amdgcn_mfma_f32_16x16x32_f16(a, b, c, 0, 0, 0);
}

// weights: normal cached loads (read-only, converted once into registers)
__device__ __forceinline__ hvec8 ldb8(const float* p) {
    hvec8 h;
#pragma unroll
    for (int j = 0; j < 8; ++j) h[j] = (f16)p[j];
    return h;
}

// cross-WG state reads: one 16B load at agent scope (sc1 -> LLC). NO waitcnt here;
// callers batch loads and then vm_wait() once before consuming.
__device__ __forceinline__ hvec8 lda8(const f16* p) {
    hvec8 v;
    asm volatile("global_load_dwordx4 %0, %1, off sc1" : "=v"(v) : "v"(p));
    return v;
}
__device__ __forceinline__ void vm_wait() {
    asm volatile("s_waitcnt vmcnt(0)" ::: "memory");
    __builtin_amdgcn_sched_barrier(0);
}

// cross-WG state writes: relaxed agent-scope atomics -> global_store sc1 (to LLC)
__device__ __forceinline__ void st2(f16* p, float a, float b) {
    union { f16 h[2]; unsigned u; } x;
    x.h[0] = (f16)a; x.h[1] = (f16)b;
    __hip_atomic_store((unsigned*)p, x.u, __ATOMIC_RELAXED, __HIP_MEMORY_SCOPE_AGENT);
}

__device__ __forceinline__ float sigf(float x) { return 1.f / (1.f + __expf(-x)); }
__device__ __forceinline__ float thf(float x) {
    x = fminf(15.f, fmaxf(-15.f, x));
    float e = __expf(2.f * x);
    return (e - 1.f) / (e + 1.f);
}

// RED row stride 132 (2-way bank conflicts only)
#define RED(t, m, w, n)  red[(((t)*16 + (m))*132) + ((w)*16) + (n)]

// sum of the 8 per-wave partials for one gate column (same tree as old RED2 pass)
__device__ __forceinline__ float sum8(const float* p) {
    return ((p[0] + p[16]) + (p[32] + p[48])) + ((p[64] + p[80]) + (p[96] + p[112]));
}

__global__ void __launch_bounds__(512, 1)
seq2seq_kernel(const float* __restrict__ enc_h, const float* __restrict__ enc_c,
               const float* __restrict__ emb_W,
               const float* __restrict__ dWih0, const float* __restrict__ dWhh0,
               const float* __restrict__ dbih0, const float* __restrict__ dbhh0,
               const float* __restrict__ dWih1, const float* __restrict__ dWhh1,
               const float* __restrict__ dbih1, const float* __restrict__ dbhh1,
               const float* __restrict__ eWih, const float* __restrict__ eWhh,
               const float* __restrict__ ebih, const float* __restrict__ ebhh,
               float* __restrict__ out, char* __restrict__ ws)
{
    const int tid  = threadIdx.x;
    const int wave = tid >> 6, lane = tid & 63;
    const int wg   = blockIdx.x;
    const int bg   = wg >> 7;        // decoder batch group (batches 16*bg..16*bg+15)
    const int g    = wg & 127;       // index within decoder group
    const int n16  = lane & 15;
    const int kq   = (lane >> 4) * 8;

    unsigned* flags  = (unsigned*)ws;          // 256 x 16B
    unsigned* myflag = flags + (size_t)wg * 4;

    f16* H0  = (f16*)(ws + WS_H0);    // [2 par][32][1024]
    f16* H1  = (f16*)(ws + WS_H1);    // [2 par][32][1024]
    f16* HE  = (f16*)(ws + WS_HE);    // [2 dir][2 par][32][512]
    f16* DEC = (f16*)(ws + WS_DEC);   // [256][32][1024]
    f16* Y0  = (f16*)(ws + WS_Y0);    // [256][32][1024]

    __shared__ float red[64 * 132];
    __shared__ float cdec[2][8][16];
    __shared__ float cenc[16][16];
    __shared__ float pre0_l[32];
    __shared__ float bias1_l[32];
    __shared__ float biasE_l[64];

    unsigned cnt = 0;
    // barrier over flags[base .. base+width). All WGs in a poll-set execute the
    // SAME bar-call sequence, so one monotone epoch per WG serves all domains.
    auto bar = [&](int base, int width) {
        const unsigned tgt = ++cnt;
        __syncthreads();   // drains this WG's visible stores before flag arrival
        if (wave == 0) {
            if (lane == 0)
                __hip_atomic_store(myflag, tgt, __ATOMIC_RELAXED, __HIP_MEMORY_SCOPE_AGENT);
            const unsigned* p0 = flags + (size_t)(base + (lane & (width - 1))) * 4;
            for (;;) {
                unsigned a = __hip_atomic_load(p0, __ATOMIC_RELAXED, __HIP_MEMORY_SCOPE_AGENT);
                if (width > 64) {
                    unsigned b = __hip_atomic_load(p0 + 64 * 4, __ATOMIC_RELAXED, __HIP_MEMORY_SCOPE_AGENT);
                    a = a < b ? a : b;
                    if (width > 128) {
                        unsigned c2 = __hip_atomic_load(p0 + 128 * 4, __ATOMIC_RELAXED, __HIP_MEMORY_SCOPE_AGENT);
                        unsigned d2 = __hip_atomic_load(p0 + 192 * 4, __ATOMIC_RELAXED, __HIP_MEMORY_SCOPE_AGENT);
                        a = a < c2 ? a : c2;
                        a = a < d2 ? a : d2;
                    }
                }
                if (__all((int)(a >= tgt))) break;
            }
        }
        __syncthreads();
    };

    // ---------------- P0: decoder weight fragments -> registers -----------------
    const int u0 = g * 8;
    hvec8 bL0[2][4], bL1[2][8];
    {
        const int gate = n16 >> 2, uu = n16 & 3;
#pragma unroll
        for (int t = 0; t < 2; ++t) {
            const int r = gate * 1024 + u0 + t * 4 + uu;
#pragma unroll
            for (int s = 0; s < 4; ++s)
                bL0[t][s] = ldb8(dWhh0 + (size_t)r * 1024 + wave * 128 + s * 32 + kq);
#pragma unroll
            for (int s = 0; s < 8; ++s) {
                const int k1 = wave * 256 + s * 32;
                bL1[t][s] = (k1 < 1024)
                    ? ldb8(dWih1 + (size_t)r * 1024 + k1 + kq)
                    : ldb8(dWhh1 + (size_t)r * 1024 + (k1 - 1024) + kq);
            }
        }
    }
    // ---------------- P0: state init + pre0/biases -------------------------------
    if (tid < 128) {
        const int which = tid >> 6, q = tid & 63, j = q >> 4, m = q & 15;
        const int b = bg * 16 + m, u = u0 + 2 * j;
        const float* src_c = enc_c + (size_t)(which * 32 + b) * 1024 + u;
        const float* src_h = enc_h + (size_t)(which * 32 + b) * 1024 + u;
        cdec[which][2 * j][m]     = src_c[0];
        cdec[which][2 * j + 1][m] = src_c[1];
        f16* dst = which ? H1 : H0;
        st2(dst + (size_t)(32 + b) * 1024 + u, src_h[0], src_h[1]);  // parity 1
    }
    if (tid < 32) {
        const int t = tid >> 4, nn = tid & 15;
        const int r = (nn >> 2) * 1024 + u0 + t * 4 + (nn & 3);
        const float* x0 = emb_W + 512;          // emb_W[BOS=1]
        float s = dbih0[r] + dbhh0[r];
        const float* wr = dWih0 + (size_t)r * 512;
        for (int k = 0; k < 512; ++k) s += wr[k] * x0[k];
        pre0_l[tid]  = s;
        bias1_l[tid] = dbih1[r] + dbhh1[r];
    }
    bar(bg * 128, 128);

    // ---------------- decoder: 257 pipelined ticks -------------------------------
    for (int tau = 0; tau <= 256; ++tau) {
        const int prd = (tau + 1) & 1;   // h0 read parity; h1 write parity
        const int pwr = tau & 1;         // h0 write parity; h1 read parity
        fvec4 acc[4];
#pragma unroll
        for (int i = 0; i < 4; ++i) acc[i] = 0;
        const int m = n16;
        // ---- batch-issue all fragment loads, then one wait, then MFMA cluster ----
        hvec8 a0f[4], a1f[8];
        if (tau < 256) {
            const f16* a0 = H0 + (size_t)(prd * 32 + bg * 16 + m) * 1024 + wave * 128 + kq;
#pragma unroll
            for (int s = 0; s < 4; ++s) a0f[s] = lda8(a0 + s * 32);
        }
        if (tau >= 1) {
            const f16* a1 = (wave < 4)
                ? H0 + (size_t)(prd * 32 + bg * 16 + m) * 1024 + wave * 256 + kq
                : H1 + (size_t)(pwr * 32 + bg * 16 + m) * 1024 + (wave - 4) * 256 + kq;
#pragma unroll
            for (int s = 0; s < 8; ++s) a1f[s] = lda8(a1 + s * 32);
        }
        vm_wait();
        if (tau < 256) {
#pragma unroll
            for (int s = 0; s < 4; ++s) {
                acc[0] = mf(a0f[s], bL0[0][s], acc[0]);
                acc[1] = mf(a0f[s], bL0[1][s], acc[1]);
            }
        }
        if (tau >= 1) {
#pragma unroll
            for (int s = 0; s < 8; ++s) {
                acc[2] = mf(a1f[s], bL1[0][s], acc[2]);
                acc[3] = mf(a1f[s], bL1[1][s], acc[3]);
            }
        }
        {
            const int mg = lane >> 4;
#pragma unroll
            for (int t = 0; t < 4; ++t)
#pragma unroll
                for (int r = 0; r < 4; ++r)
                    RED(t, mg * 4 + r, wave, n16) = acc[t][r];
        }
        __syncthreads();
        if (tid < 64 && tau < 256) {                       // L0 pointwise (wave 0)
            const int j = tid >> 4, m2 = tid & 15, t = j >> 1;
            float hh[2];
#pragma unroll
            for (int e = 0; e < 2; ++e) {
                const int uu = 2 * j + e, ul = uu & 3;
                const float* p = &RED(t, m2, 0, ul);
                const float gi = sum8(p)      + pre0_l[t * 16 + ul];
                const float gf = sum8(p + 4)  + pre0_l[t * 16 + 4 + ul];
                const float gg = sum8(p + 8)  + pre0_l[t * 16 + 8 + ul];
                const float go = sum8(p + 12) + pre0_l[t * 16 + 12 + ul];
                float c = cdec[0][uu][m2];
                c = sigf(gf) * c + sigf(gi) * thf(gg);
                hh[e] = sigf(go) * thf(c);
                cdec[0][uu][m2] = c;
            }
            st2(H0 + (size_t)(pwr * 32 + bg * 16 + m2) * 1024 + u0 + 2 * j, hh[0], hh[1]);
        }
        if (tid >= 64 && tid < 128 && tau >= 1) {          // L1 pointwise (wave 1)
            const int q = tid - 64;
            const int j = q >> 4, m2 = q & 15, t = j >> 1;
            float hh[2];
#pragma unroll
            for (int e = 0; e < 2; ++e) {
                const int uu = 2 * j + e, ul = uu & 3;
                const float* p = &RED(2 + t, m2, 0, ul);
                const float gi = sum8(p)      + bias1_l[t * 16 + ul];
                const float gf = sum8(p + 4)  + bias1_l[t * 16 + 4 + ul];
                const float gg = sum8(p + 8)  + bias1_l[t * 16 + 8 + ul];
                const float go = sum8(p + 12) + bias1_l[t * 16 + 12 + ul];
                float c = cdec[1][uu][m2];
                c = sigf(gf) * c + sigf(gi) * thf(gg);
                hh[e] = sigf(go) * thf(c);
                cdec[1][uu][m2] = c;
            }
            const int b = bg * 16 + m2, u = u0 + 2 * j;
            st2(H1 + (size_t)(prd * 32 + b) * 1024 + u, hh[0], hh[1]);
            st2(DEC + ((size_t)(tau - 1) * 32 + b) * 1024 + u, hh[0], hh[1]);
        }
        bar(bg * 128, 128);
    }

    // one-time grid barrier: DEC from BOTH bgs visible to everyone
    bar(0, 256);
    if (wg >= 128) return;   // decoder-only WGs done

    // ---------------- encoder: 2 layers x 256 ticks, U=16, 32 WGs/domain ---------
    const int bg2 = wg >> 6;            // encoder batch group
    const int dir = (wg >> 5) & 1;
    const int ge  = wg & 31;
    const int ue0 = ge * 16;
    const int dbase = bg2 * 64 + dir * 32;
    for (int l = 0; l < 2; ++l) {
        hvec8 bE[4][6];
        {
            const int gate = n16 >> 2, uu = n16 & 3;
            const float* Wih = eWih + (size_t)(l * 2 + dir) * 2048 * 1024;
            const float* Whh = eWhh + (size_t)(l * 2 + dir) * 2048 * 512;
#pragma unroll
            for (int t = 0; t < 4; ++t) {
                const int r = gate * 512 + ue0 + t * 4 + uu;
#pragma unroll
                for (int s = 0; s < 6; ++s) {
                    const int kb = wave * 192 + s * 32;
                    bE[t][s] = (kb < 1024)
                        ? ldb8(Wih + (size_t)r * 1024 + kb + kq)
                        : ldb8(Whh + (size_t)r * 512 + (kb - 1024) + kq);
                }
            }
        }
        if (tid < 64) {
            const int t = tid >> 4, nn = tid & 15;
            const int r = (nn >> 2) * 512 + ue0 + t * 4 + (nn & 3);
            biasE_l[tid] = ebih[(size_t)(l * 2 + dir) * 2048 + r]
                         + ebhh[(size_t)(l * 2 + dir) * 2048 + r];
        }
        if (tid < 128) {
            const int j = tid >> 4, m = tid & 15;
            cenc[2 * j][m] = 0.f;
            cenc[2 * j + 1][m] = 0.f;
            st2(HE + (size_t)((dir * 2 + 1) * 32 + bg2 * 16 + m) * 512 + ue0 + 2 * j, 0.f, 0.f);
        }
        bar(dbase, 32);
        const f16* yprev = (l == 0) ? DEC : Y0;
        // prologue: prefetch y fragments for tau=0
        hvec8 ypf[6];
        {
            const int t0 = dir ? 255 : 0;
            const int b = bg2 * 16 + n16;
#pragma unroll
            for (int s = 0; s < 6; ++s) {
                const int kb = wave * 192 + s * 32;
                if (kb < 1024)
                    ypf[s] = lda8(yprev + ((size_t)t0 * 32 + b) * 1024 + kb + kq);
            }
        }
        for (int tau = 0; tau < 256; ++tau) {
            const int t = dir ? (255 - tau) : tau;
            const int prd = (tau + 1) & 1, pwr = tau & 1;
            const int b = bg2 * 16 + n16;
            // recurrent HE loads (this tick's critical path)
            hvec8 hef[6];
#pragma unroll
            for (int s = 0; s < 6; ++s) {
                const int kb = wave * 192 + s * 32;
                if (kb >= 1024)
                    hef[s] = lda8(HE + (size_t)((dir * 2 + prd) * 32 + b) * 512 + (kb - 1024) + kq);
            }
            vm_wait();   // also covers last tick's y-prefetch
            fvec4 acc2[4];
#pragma unroll
            for (int i = 0; i < 4; ++i) acc2[i] = 0;
#pragma unroll
            for (int s = 0; s < 6; ++s) {
                const int kb = wave * 192 + s * 32;
                const hvec8 a = (kb < 1024) ? ypf[s] : hef[s];
                acc2[0] = mf(a, bE[0][s], acc2[0]);
                acc2[1] = mf(a, bE[1][s], acc2[1]);
                acc2[2] = mf(a, bE[2][s], acc2[2]);
                acc2[3] = mf(a, bE[3][s], acc2[3]);
            }
            // prefetch next tick's y fragments (schedule is known)
            if (tau < 255) {
                const int tn = dir ? (t - 1) : (t + 1);
#pragma unroll
                for (int s = 0; s < 6; ++s) {
                    const int kb = wave * 192 + s * 32;
                    if (kb < 1024)
                        ypf[s] = lda8(yprev + ((size_t)tn * 32 + b) * 1024 + kb + kq);
                }
            }
            const int mg = lane >> 4;
#pragma unroll
            for (int tt = 0; tt < 4; ++tt)
#pragma unroll
                for (int r = 0; r < 4; ++r)
                    RED(tt, mg * 4 + r, wave, n16) = acc2[tt][r];
            __syncthreads();
            if (tid < 128) {
                const int j = tid >> 4, m2 = tid & 15;
                float hh[2], cc[2];
#pragma unroll
                for (int e = 0; e < 2; ++e) {
                    const int uu = 2 * j + e, tt = uu >> 2, ul = uu & 3;
                    const float* p = &RED(tt, m2, 0, ul);
                    const float gi = sum8(p)      + biasE_l[tt * 16 + ul];
                    const float gf = sum8(p + 4)  + biasE_l[tt * 16 + 4 + ul];
                    const float gg = sum8(p + 8)  + biasE_l[tt * 16 + 8 + ul];
                    const float go = sum8(p + 12) + biasE_l[tt * 16 + 12 + ul];
                    float c = cenc[uu][m2];
                    c = sigf(gf) * c + sigf(gi) * thf(gg);
                    hh[e] = sigf(go) * thf(c);
                    cc[e] = c;
                    cenc[uu][m2] = c;
                }
                const int b2 = bg2 * 16 + m2, u = ue0 + 2 * j;
                st2(HE + (size_t)((dir * 2 + pwr) * 32 + b2) * 512 + u, hh[0], hh[1]);
                if (l == 0) {
                    st2(Y0 + ((size_t)t * 32 + b2) * 1024 + dir * 512 + u, hh[0], hh[1]);
                } else {
                    float* o = out + ((size_t)b2 * 256 + t) * 1024 + dir * 512 + u;
                    o[0] = hh[0]; o[1] = hh[1];
                    if (tau == 255) {   // final states -> dec_h / dec_c
                        const int col = dir * 512 + u;
                        float* oh = out + 8388608 + (size_t)b2 * 1024 + col;
                        float* oc = out + 8454144 + (size_t)b2 * 1024 + col;
                        oh[0] = hh[0]; oh[1] = hh[1];
                        oh[32768] = hh[0]; oh[32769] = hh[1];
                        oc[0] = cc[0]; oc[1] = cc[1];
                        oc[32768] = cc[0]; oc[32769] = cc[1];
                    }
                }
            }
            bar(dbase, 32);
        }
        if (l == 0) bar(bg2 * 64, 64);  // Y0 (both dirs of this bg) complete
    }
}

extern "C" void kernel_launch(void* const* d_in, const int* in_sizes, int n_in,
                              void* d_out, int out_size, void* d_ws, size_t ws_size,
                              hipStream_t stream) {
    (void)in_sizes; (void)n_in; (void)out_size; (void)ws_size;
    const float* enc_h = (const float*)d_in[1];
    const float* enc_c = (const float*)d_in[2];
    const float* emb_W = (const float*)d_in[4];
    const float* dWih0 = (const float*)d_in[5];
    const float* dWhh0 = (const float*)d_in[6];
    const float* dbih0 = (const float*)d_in[7];
    const float* dbhh0 = (const float*)d_in[8];
    const float* dWih1 = (const float*)d_in[9];
    const float* dWhh1 = (const float*)d_in[10];
    const float* dbih1 = (const float*)d_in[11];
    const float* dbhh1 = (const float*)d_in[12];
    const float* eWih  = (const float*)d_in[13];
    const float* eWhh  = (const float*)d_in[14];
    const float* ebih  = (const float*)d_in[15];
    const float* ebhh  = (const float*)d_in[16];
    float* outp = (float*)d_out;
    char* ws = (char*)d_ws;

    // zero the epoch flags (ws is re-poisoned before every launch)
    hipMemsetAsync(d_ws, 0, 4096, stream);

    void* args[] = {&enc_h, &enc_c, &emb_W, &dWih0, &dWhh0, &dbih0, &dbhh0,
                    &dWih1, &dWhh1, &dbih1, &dbhh1, &eWih, &eWhh, &ebih, &ebhh,
                    &outp, &ws};
    hipLaunchCooperativeKernel((const void*)seq2seq_kernel, dim3(256), dim3(512),
                               args, 0, stream);
}

// Round 5
// 3552.488 us; speedup vs baseline: 4.0349x; 1.0671x over previous
//
#include <hip/hip_runtime.h>

// Seq2SeqBridge: persistent cooperative kernel, f16 MFMA, register-resident weights.
// R5 = R4's flag-spreading experiment with the lifetime bug fixed.
// R4 failure: flags live in OUT's dec_h region, but domains finish asynchronously;
// early-finishing WGs' final dec_h stores clobbered flags other domains were still
// polling (and vice versa). Fix: final dec_h/dec_c payloads are held in REGISTERS
// through a terminal 128-wide encoder barrier (the last poll anywhere); only after
// it does anyone store to the flag region. All barrier-epoch sequences audited:
// every encoder WG executes the identical barrier sequence; decoder-only WG flags
// (dwords 8192+) are never polled after the one grid barrier.
// Changes vs R3 under test:
//  1) 256B-stride flags -> each WG's flag on its own cache line (poll contention).
//  2) Wave 0 = dedicated barrier wave (pointwise on waves 1-2).
//  3) Non-critical stores (DEC, Y0, out, final states) deferred off the ack path.
// Data protocol unchanged: sc1 agent-scope everywhere, no cache fences.

typedef _Float16 f16;
typedef _Float16 hvec8 __attribute__((ext_vector_type(8)));
typedef float fvec4 __attribute__((ext_vector_type(4)));

#define WS_H0   4096
#define WS_H1   135168
#define WS_HE   266240
#define WS_DEC  397312
#define WS_Y0   17174528
// flags: 256 x 256B in OUT at byte 33554432 (dec_h[0][0..15] rows -- dead until
// the post-terminal-barrier final-state stores).

__device__ __forceinline__ fvec4 mf(hvec8 a, hvec8 b, fvec4 c) {
    return __builtin_amdgcn_mfma_f32_16x16x32_f16(a, b, c, 0, 0, 0);
}

// weights: normal cached loads (read-only, converted once into registers)
__device__ __forceinline__ hvec8 ldb8(const float* p) {
    hvec8 h;
#pragma unroll
    for (int j = 0; j < 8; ++j) h[j] = (f16)p[j];
    return h;
}

// cross-WG state reads: one 16B load at agent scope (sc1 -> LLC). NO waitcnt here;
// callers batch loads and then vm_wait() once before consuming.
__device__ __forceinline__ hvec8 lda8(const f16* p) {
    hvec8 v;
    asm volatile("global_load_dwordx4 %0, %1, off sc1" : "=v"(v) : "v"(p));
    return v;
}
__device__ __forceinline__ void vm_wait() {
    asm volatile("s_waitcnt vmcnt(0)" ::: "memory");
    __builtin_amdgcn_sched_barrier(0);
}

// cross-WG state writes: relaxed agent-scope atomics -> global_store sc1 (to LLC)
__device__ __forceinline__ void st2(f16* p, float a, float b) {
    union { f16 h[2]; unsigned u; } x;
    x.h[0] = (f16)a; x.h[1] = (f16)b;
    __hip_atomic_store((unsigned*)p, x.u, __ATOMIC_RELAXED, __HIP_MEMORY_SCOPE_AGENT);
}

__device__ __forceinline__ float sigf(float x) { return 1.f / (1.f + __expf(-x)); }
__device__ __forceinline__ float thf(float x) {
    x = fminf(15.f, fmaxf(-15.f, x));
    float e = __expf(2.f * x);
    return (e - 1.f) / (e + 1.f);
}

// RED row stride 132 (2-way bank conflicts only)
#define RED(t, m, w, n)  red[(((t)*16 + (m))*132) + ((w)*16) + (n)]

// sum of the 8 per-wave partials for one gate column
__device__ __forceinline__ float sum8(const float* p) {
    return ((p[0] + p[16]) + (p[32] + p[48])) + ((p[64] + p[80]) + (p[96] + p[112]));
}

__global__ void __launch_bounds__(512, 1)
seq2seq_kernel(const float* __restrict__ enc_h, const float* __restrict__ enc_c,
               const float* __restrict__ emb_W,
               const float* __restrict__ dWih0, const float* __restrict__ dWhh0,
               const float* __restrict__ dbih0, const float* __restrict__ dbhh0,
               const float* __restrict__ dWih1, const float* __restrict__ dWhh1,
               const float* __restrict__ dbih1, const float* __restrict__ dbhh1,
               const float* __restrict__ eWih, const float* __restrict__ eWhh,
               const float* __restrict__ ebih, const float* __restrict__ ebhh,
               float* __restrict__ out, char* __restrict__ ws)
{
    const int tid  = threadIdx.x;
    const int wave = tid >> 6, lane = tid & 63;
    const int wg   = blockIdx.x;
    const int bg   = wg >> 7;        // decoder batch group (batches 16*bg..16*bg+15)
    const int g    = wg & 127;       // index within decoder group
    const int n16  = lane & 15;
    const int kq   = (lane >> 4) * 8;

    // spread flags: one per WG, 256B (64-dword) stride, in OUT's dec_h region
    unsigned* flags  = (unsigned*)(out + 8388608);
    unsigned* myflag = flags + (size_t)wg * 64;

    f16* H0  = (f16*)(ws + WS_H0);    // [2 par][32][1024]
    f16* H1  = (f16*)(ws + WS_H1);    // [2 par][32][1024]
    f16* HE  = (f16*)(ws + WS_HE);    // [2 dir][2 par][32][512]
    f16* DEC = (f16*)(ws + WS_DEC);   // [256][32][1024]
    f16* Y0  = (f16*)(ws + WS_Y0);    // [256][32][1024]

    __shared__ float red[64 * 132];
    __shared__ float cdec[2][8][16];
    __shared__ float cenc[16][16];
    __shared__ float pre0_l[32];
    __shared__ float bias1_l[32];
    __shared__ float biasE_l[64];

    unsigned cnt = 0;   // used only by wave 0 (identical sequence in every WG)
    // wave-0-only: arrive (flag := tgt) then poll flags[base..base+width)
    auto barpoll = [&](int base, int width, unsigned tgt) {
        if (lane == 0)
            __hip_atomic_store(myflag, tgt, __ATOMIC_RELAXED, __HIP_MEMORY_SCOPE_AGENT);
        const unsigned* p0 = flags + (size_t)(base + (lane & (width - 1))) * 64;
        for (;;) {
            unsigned a = __hip_atomic_load(p0, __ATOMIC_RELAXED, __HIP_MEMORY_SCOPE_AGENT);
            if (width > 64) {
                unsigned b = __hip_atomic_load(p0 + 64 * 64, __ATOMIC_RELAXED, __HIP_MEMORY_SCOPE_AGENT);
                a = a < b ? a : b;
                if (width > 128) {
                    unsigned c2 = __hip_atomic_load(p0 + 128 * 64, __ATOMIC_RELAXED, __HIP_MEMORY_SCOPE_AGENT);
                    unsigned d2 = __hip_atomic_load(p0 + 192 * 64, __ATOMIC_RELAXED, __HIP_MEMORY_SCOPE_AGENT);
                    a = a < c2 ? a : c2;
                    a = a < d2 ? a : d2;
                }
            }
            if (__all((int)(a >= tgt))) break;
            __builtin_amdgcn_s_sleep(1);
        }
    };

    // ---------------- P0: decoder weight fragments -> registers -----------------
    const int u0 = g * 8;
    hvec8 bL0[2][4], bL1[2][8];
    {
        const int gate = n16 >> 2, uu = n16 & 3;
#pragma unroll
        for (int t = 0; t < 2; ++t) {
            const int r = gate * 1024 + u0 + t * 4 + uu;
#pragma unroll
            for (int s = 0; s < 4; ++s)
                bL0[t][s] = ldb8(dWhh0 + (size_t)r * 1024 + wave * 128 + s * 32 + kq);
#pragma unroll
            for (int s = 0; s < 8; ++s) {
                const int k1 = wave * 256 + s * 32;
                bL1[t][s] = (k1 < 1024)
                    ? ldb8(dWih1 + (size_t)r * 1024 + k1 + kq)
                    : ldb8(dWhh1 + (size_t)r * 1024 + (k1 - 1024) + kq);
            }
        }
    }
    // ---------------- P0: state init + pre0/biases -------------------------------
    if (tid < 128) {
        const int which = tid >> 6, q = tid & 63, j = q >> 4, m = q & 15;
        const int b = bg * 16 + m, u = u0 + 2 * j;
        const float* src_c = enc_c + (size_t)(which * 32 + b) * 1024 + u;
        const float* src_h = enc_h + (size_t)(which * 32 + b) * 1024 + u;
        cdec[which][2 * j][m]     = src_c[0];
        cdec[which][2 * j + 1][m] = src_c[1];
        f16* dst = which ? H1 : H0;
        st2(dst + (size_t)(32 + b) * 1024 + u, src_h[0], src_h[1]);  // parity 1
    }
    if (tid < 32) {
        const int t = tid >> 4, nn = tid & 15;
        const int r = (nn >> 2) * 1024 + u0 + t * 4 + (nn & 3);
        const float* x0 = emb_W + 512;          // emb_W[BOS=1]
        float s = dbih0[r] + dbhh0[r];
        const float* wr = dWih0 + (size_t)r * 512;
        for (int k = 0; k < 512; ++k) s += wr[k] * x0[k];
        pre0_l[tid]  = s;
        bias1_l[tid] = dbih1[r] + dbhh1[r];
    }
    __syncthreads();
    if (wave == 0) barpoll(bg * 128, 128, ++cnt);
    __syncthreads();

    // ---------------- decoder: 257 pipelined ticks -------------------------------
    for (int tau = 0; tau <= 256; ++tau) {
        const int prd = (tau + 1) & 1;   // h0 read parity; h1 write parity
        const int pwr = tau & 1;         // h0 write parity; h1 read parity
        fvec4 acc[4];
#pragma unroll
        for (int i = 0; i < 4; ++i) acc[i] = 0;
        const int m = n16;
        // ---- batch-issue all fragment loads, then one wait, then MFMA cluster ----
        hvec8 a0f[4], a1f[8];
        if (tau < 256) {
            const f16* a0 = H0 + (size_t)(prd * 32 + bg * 16 + m) * 1024 + wave * 128 + kq;
#pragma unroll
            for (int s = 0; s < 4; ++s) a0f[s] = lda8(a0 + s * 32);
        }
        if (tau >= 1) {
            const f16* a1 = (wave < 4)
                ? H0 + (size_t)(prd * 32 + bg * 16 + m) * 1024 + wave * 256 + kq
                : H1 + (size_t)(pwr * 32 + bg * 16 + m) * 1024 + (wave - 4) * 256 + kq;
#pragma unroll
            for (int s = 0; s < 8; ++s) a1f[s] = lda8(a1 + s * 32);
        }
        vm_wait();
        if (tau < 256) {
#pragma unroll
            for (int s = 0; s < 4; ++s) {
                acc[0] = mf(a0f[s], bL0[0][s], acc[0]);
                acc[1] = mf(a0f[s], bL0[1][s], acc[1]);
            }
        }
        if (tau >= 1) {
#pragma unroll
            for (int s = 0; s < 8; ++s) {
                acc[2] = mf(a1f[s], bL1[0][s], acc[2]);
                acc[3] = mf(a1f[s], bL1[1][s], acc[3]);
            }
        }
        {
            const int mg = lane >> 4;
#pragma unroll
            for (int t = 0; t < 4; ++t)
#pragma unroll
                for (int r = 0; r < 4; ++r)
                    RED(t, mg * 4 + r, wave, n16) = acc[t][r];
        }
        __syncthreads();
        float s0 = 0.f, s1 = 0.f;           // deferred DEC payload (wave 2)
        int   sm2 = 0, sj = 0;
        if (wave == 1 && tau < 256) {                      // L0 pointwise (wave 1)
            const int q = tid - 64;
            const int j = q >> 4, m2 = q & 15, t = j >> 1;
            float hh[2];
#pragma unroll
            for (int e = 0; e < 2; ++e) {
                const int uu = 2 * j + e, ul = uu & 3;
                const float* p = &RED(t, m2, 0, ul);
                const float gi = sum8(p)      + pre0_l[t * 16 + ul];
                const float gf = sum8(p + 4)  + pre0_l[t * 16 + 4 + ul];
                const float gg = sum8(p + 8)  + pre0_l[t * 16 + 8 + ul];
                const float go = sum8(p + 12) + pre0_l[t * 16 + 12 + ul];
                float c = cdec[0][uu][m2];
                c = sigf(gf) * c + sigf(gi) * thf(gg);
                hh[e] = sigf(go) * thf(c);
                cdec[0][uu][m2] = c;
            }
            st2(H0 + (size_t)(pwr * 32 + bg * 16 + m2) * 1024 + u0 + 2 * j, hh[0], hh[1]);
        }
        if (wave == 2 && tau >= 1) {                       // L1 pointwise (wave 2)
            const int q = tid - 128;
            const int j = q >> 4, m2 = q & 15, t = j >> 1;
            float hh[2];
#pragma unroll
            for (int e = 0; e < 2; ++e) {
                const int uu = 2 * j + e, ul = uu & 3;
                const float* p = &RED(2 + t, m2, 0, ul);
                const float gi = sum8(p)      + bias1_l[t * 16 + ul];
                const float gf = sum8(p + 4)  + bias1_l[t * 16 + 4 + ul];
                const float gg = sum8(p + 8)  + bias1_l[t * 16 + 8 + ul];
                const float go = sum8(p + 12) + bias1_l[t * 16 + 12 + ul];
                float c = cdec[1][uu][m2];
                c = sigf(gf) * c + sigf(gi) * thf(gg);
                hh[e] = sigf(go) * thf(c);
                cdec[1][uu][m2] = c;
            }
            const int b = bg * 16 + m2, u = u0 + 2 * j;
            st2(H1 + (size_t)(prd * 32 + b) * 1024 + u, hh[0], hh[1]);
            s0 = hh[0]; s1 = hh[1]; sm2 = m2; sj = j;      // DEC deferred
        }
        __syncthreads();                                   // drains H0/H1 (+ prev DEC)
        if (wave == 0) {
            barpoll(bg * 128, 128, ++cnt);
        } else if (wave == 2 && tau >= 1) {
            st2(DEC + ((size_t)(tau - 1) * 32 + bg * 16 + sm2) * 1024 + u0 + 2 * sj, s0, s1);
        }
        __syncthreads();
    }

    // one-time grid barrier: DEC from BOTH bgs visible to everyone
    __syncthreads();                 // drains tau=256's deferred DEC
    if (wave == 0) barpoll(0, 256, ++cnt);
    __syncthreads();
    if (wg >= 128) return;   // decoder-only WGs done (their flags never polled again)

    // ---------------- encoder: 2 layers x 256 ticks, U=16, 32 WGs/domain ---------
    const int bg2 = wg >> 6;            // encoder batch group
    const int dir = (wg >> 5) & 1;
    const int ge  = wg & 31;
    const int ue0 = ge * 16;
    const int dbase = bg2 * 64 + dir * 32;
    float fdh0 = 0.f, fdh1 = 0.f, fdc0 = 0.f, fdc1 = 0.f;  // final-state payload
    int   fdm2 = 0, fdj = 0;                               // (written post-terminal)
    for (int l = 0; l < 2; ++l) {
        hvec8 bE[4][6];
        {
            const int gate = n16 >> 2, uu = n16 & 3;
            const float* Wih = eWih + (size_t)(l * 2 + dir) * 2048 * 1024;
            const float* Whh = eWhh + (size_t)(l * 2 + dir) * 2048 * 512;
#pragma unroll
            for (int t = 0; t < 4; ++t) {
                const int r = gate * 512 + ue0 + t * 4 + uu;
#pragma unroll
                for (int s = 0; s < 6; ++s) {
                    const int kb = wave * 192 + s * 32;
                    bE[t][s] = (kb < 1024)
                        ? ldb8(Wih + (size_t)r * 1024 + kb + kq)
                        : ldb8(Whh + (size_t)r * 512 + (kb - 1024) + kq);
                }
            }
        }
        if (tid < 64) {
            const int t = tid >> 4, nn = tid & 15;
            const int r = (nn >> 2) * 512 + ue0 + t * 4 + (nn & 3);
            biasE_l[tid] = ebih[(size_t)(l * 2 + dir) * 2048 + r]
                         + ebhh[(size_t)(l * 2 + dir) * 2048 + r];
        }
        if (tid < 128) {
            const int j = tid >> 4, m = tid & 15;
            cenc[2 * j][m] = 0.f;
            cenc[2 * j + 1][m] = 0.f;
            st2(HE + (size_t)((dir * 2 + 1) * 32 + bg2 * 16 + m) * 512 + ue0 + 2 * j, 0.f, 0.f);
        }
        __syncthreads();
        if (wave == 0) barpoll(dbase, 32, ++cnt);
        __syncthreads();
        const f16* yprev = (l == 0) ? DEC : Y0;
        // prologue: prefetch y fragments for tau=0
        hvec8 ypf[6];
        {
            const int t0 = dir ? 255 : 0;
            const int b = bg2 * 16 + n16;
#pragma unroll
            for (int s = 0; s < 6; ++s) {
                const int kb = wave * 192 + s * 32;
                if (kb < 1024)
                    ypf[s] = lda8(yprev + ((size_t)t0 * 32 + b) * 1024 + kb + kq);
            }
        }
        for (int tau = 0; tau < 256; ++tau) {
            const int t = dir ? (255 - tau) : tau;
            const int prd = (tau + 1) & 1, pwr = tau & 1;
            const int b = bg2 * 16 + n16;
            // recurrent HE loads (this tick's critical path)
            hvec8 hef[6];
#pragma unroll
            for (int s = 0; s < 6; ++s) {
                const int kb = wave * 192 + s * 32;
                if (kb >= 1024)
                    hef[s] = lda8(HE + (size_t)((dir * 2 + prd) * 32 + b) * 512 + (kb - 1024) + kq);
            }
            vm_wait();   // also covers last tick's y-prefetch
            fvec4 acc2[4];
#pragma unroll
            for (int i = 0; i < 4; ++i) acc2[i] = 0;
#pragma unroll
            for (int s = 0; s < 6; ++s) {
                const int kb = wave * 192 + s * 32;
                const hvec8 a = (kb < 1024) ? ypf[s] : hef[s];
                acc2[0] = mf(a, bE[0][s], acc2[0]);
                acc2[1] = mf(a, bE[1][s], acc2[1]);
                acc2[2] = mf(a, bE[2][s], acc2[2]);
                acc2[3] = mf(a, bE[3][s], acc2[3]);
            }
            // prefetch next tick's y fragments (schedule is known)
            if (tau < 255) {
                const int tn = dir ? (t - 1) : (t + 1);
#pragma unroll
                for (int s = 0; s < 6; ++s) {
                    const int kb = wave * 192 + s * 32;
                    if (kb < 1024)
                        ypf[s] = lda8(yprev + ((size_t)tn * 32 + b) * 1024 + kb + kq);
                }
            }
            const int mg = lane >> 4;
#pragma unroll
            for (int tt = 0; tt < 4; ++tt)
#pragma unroll
                for (int r = 0; r < 4; ++r)
                    RED(tt, mg * 4 + r, wave, n16) = acc2[tt][r];
            __syncthreads();
            float dh0 = 0.f, dh1 = 0.f, dc0 = 0.f, dc1 = 0.f;  // deferred payload
            int   dm2 = 0, dj = 0;
            if (tid >= 64 && tid < 192) {                  // pointwise (waves 1-2)
                const int q = tid - 64;
                const int j = q >> 4, m2 = q & 15;
                float hh[2], cc[2];
#pragma unroll
                for (int e = 0; e < 2; ++e) {
                    const int uu = 2 * j + e, tt = uu >> 2, ul = uu & 3;
                    const float* p = &RED(tt, m2, 0, ul);
                    const float gi = sum8(p)      + biasE_l[tt * 16 + ul];
                    const float gf = sum8(p + 4)  + biasE_l[tt * 16 + 4 + ul];
                    const float gg = sum8(p + 8)  + biasE_l[tt * 16 + 8 + ul];
                    const float go = sum8(p + 12) + biasE_l[tt * 16 + 12 + ul];
                    float c = cenc[uu][m2];
                    c = sigf(gf) * c + sigf(gi) * thf(gg);
                    hh[e] = sigf(go) * thf(c);
                    cc[e] = c;
                    cenc[uu][m2] = c;
                }
                st2(HE + (size_t)((dir * 2 + pwr) * 32 + bg2 * 16 + m2) * 512 + ue0 + 2 * j,
                    hh[0], hh[1]);
                dh0 = hh[0]; dh1 = hh[1]; dc0 = cc[0]; dc1 = cc[1];
                dm2 = m2; dj = j;
            }
            __syncthreads();                               // drains HE (+ prev deferred)
            if (wave == 0) {
                if (!(l == 1 && tau == 255)) barpoll(dbase, 32, ++cnt);
            } else if (tid >= 64 && tid < 192) {
                const int b2 = bg2 * 16 + dm2, u = ue0 + 2 * dj;
                if (l == 0) {
                    st2(Y0 + ((size_t)t * 32 + b2) * 1024 + dir * 512 + u, dh0, dh1);
                } else {
                    float* o = out + ((size_t)b2 * 256 + t) * 1024 + dir * 512 + u;
                    o[0] = dh0; o[1] = dh1;
                    if (tau == 255) {   // final states: keep in REGISTERS until the
                        fdh0 = dh0; fdh1 = dh1;            // terminal barrier below
                        fdc0 = dc0; fdc1 = dc1;
                        fdm2 = dm2; fdj = dj;
                    }
                }
            }
            __syncthreads();
        }
        if (l == 0) {                                      // Y0 (both dirs) complete
            __syncthreads();                               // drains last deferred Y0
            if (wave == 0) barpoll(bg2 * 64, 64, ++cnt);
            __syncthreads();
        }
    }
    // terminal barrier: the LAST poll anywhere. After it, the flag region is dead
    // and may be overwritten by the final dec_h/dec_c stores.
    __syncthreads();
    if (wave == 0) barpoll(0, 128, ++cnt);
    __syncthreads();
    if (tid >= 64 && tid < 192) {
        const int b2 = bg2 * 16 + fdm2;
        const int col = dir * 512 + ue0 + 2 * fdj;
        float* oh = out + 8388608 + (size_t)b2 * 1024 + col;
        float* oc = out + 8454144 + (size_t)b2 * 1024 + col;
        oh[0] = fdh0; oh[1] = fdh1;
        oh[32768] = fdh0; oh[32769] = fdh1;
        oc[0] = fdc0; oc[1] = fdc1;
        oc[32768] = fdc0; oc[32769] = fdc1;
    }
}

extern "C" void kernel_launch(void* const* d_in, const int* in_sizes, int n_in,
                              void* d_out, int out_size, void* d_ws, size_t ws_size,
                              hipStream_t stream) {
    (void)in_sizes; (void)n_in; (void)out_size; (void)ws_size;
    const float* enc_h = (const float*)d_in[1];
    const float* enc_c = (const float*)d_in[2];
    const float* emb_W = (const float*)d_in[4];
    const float* dWih0 = (const float*)d_in[5];
    const float* dWhh0 = (const float*)d_in[6];
    const float* dbih0 = (const float*)d_in[7];
    const float* dbhh0 = (const float*)d_in[8];
    const float* dWih1 = (const float*)d_in[9];
    const float* dWhh1 = (const float*)d_in[10];
    const float* dbih1 = (const float*)d_in[11];
    const float* dbhh1 = (const float*)d_in[12];
    const float* eWih  = (const float*)d_in[13];
    const float* eWhh  = (const float*)d_in[14];
    const float* ebih  = (const float*)d_in[15];
    const float* ebhh  = (const float*)d_in[16];
    float* outp = (float*)d_out;
    char* ws = (char*)d_ws;

    // zero the spread flag region (lives in OUT's dec_h area; overwritten with real
    // dec_h values only after the kernel's terminal barrier)
    hipMemsetAsync((char*)d_out + 33554432, 0, 65536, stream);

    void* args[] = {&enc_h, &enc_c, &emb_W, &dWih0, &dWhh0, &dbih0, &dbhh0,
                    &dWih1, &dWhh1, &dbih1, &dbhh1, &eWih, &eWhh, &ebih, &ebhh,
                    &outp, &ws};
    hipLaunchCooperativeKernel((const void*)seq2seq_kernel, dim3(256), dim3(512),
                               args, 0, stream);
}

// Round 6
// 3145.847 us; speedup vs baseline: 4.5565x; 1.1293x over previous
//
#include <hip/hip_runtime.h>

// Seq2SeqBridge: persistent cooperative kernel, f16 MFMA, register-resident weights.
// R6 vs R5 (3552 us): decoder domain split + decoupled chase.
//  - Decoder per bg: 64 L0-WGs (U=16) + 64 L1-WGs (U=16), SEPARATE 64-wide barrier
//    domains. h0 lives in a depth-4 ring (overlaid on Y0, dead during decoder):
//    L0 free-runs 1-2 ticks ahead (backpressure: L1-epoch >= cnt-2, lagged ->
//    pre-satisfied); L1's wait on L0 (>= cnt) is pre-satisfied since L0 leads ->
//    the h0 store-ack/flag/detect chain is OFF L1's critical path. L1's round =
//    its own h1 recurrence + 64-wide detect only.
//  - Per-tick broadcast reads halve (each WG reads only its layer's k-range).
//  - Encoder (WGs 0-127) unchanged from R5 (R3 showed its traffic isn't binding).
// Ring-reuse audit: slot (n+1)&3 last read at rounds n-2 by both domains; barrier
// gives L1 >= n before L0 enters n+1. Epochs uniform: P0(1) + 257 rounds + grid
// (259); encoder continues 260..774 exactly as R5. Flags in OUT's dec_h region
// (R5 lifetime fix: final dec_h/dec_c held in registers past the terminal poll).

typedef _Float16 f16;
typedef _Float16 hvec8 __attribute__((ext_vector_type(8)));
typedef float fvec4 __attribute__((ext_vector_type(4)));

#define WS_H1   135168
#define WS_HE   266240
#define WS_DEC  397312
#define WS_Y0   17174528
// h0 ring: [4 slot][32 b][1024] f16 = 256KB overlaid at WS_Y0 (decoder phase only)

__device__ __forceinline__ fvec4 mf(hvec8 a, hvec8 b, fvec4 c) {
    return __builtin_amdgcn_mfma_f32_16x16x32_f16(a, b, c, 0, 0, 0);
}

// weights: normal cached loads (read-only, converted once into registers)
__device__ __forceinline__ hvec8 ldb8(const float* p) {
    hvec8 h;
#pragma unroll
    for (int j = 0; j < 8; ++j) h[j] = (f16)p[j];
    return h;
}

// cross-WG state reads: one 16B load at agent scope (sc1 -> LLC). NO waitcnt here;
// callers batch loads and then vm_wait() once before consuming.
__device__ __forceinline__ hvec8 lda8(const f16* p) {
    hvec8 v;
    asm volatile("global_load_dwordx4 %0, %1, off sc1" : "=v"(v) : "v"(p));
    return v;
}
__device__ __forceinline__ void vm_wait() {
    asm volatile("s_waitcnt vmcnt(0)" ::: "memory");
    __builtin_amdgcn_sched_barrier(0);
}

// cross-WG state writes: relaxed agent-scope atomics -> global_store sc1 (to LLC)
__device__ __forceinline__ void st2(f16* p, float a, float b) {
    union { f16 h[2]; unsigned u; } x;
    x.h[0] = (f16)a; x.h[1] = (f16)b;
    __hip_atomic_store((unsigned*)p, x.u, __ATOMIC_RELAXED, __HIP_MEMORY_SCOPE_AGENT);
}

__device__ __forceinline__ float sigf(float x) { return 1.f / (1.f + __expf(-x)); }
__device__ __forceinline__ float thf(float x) {
    x = fminf(15.f, fmaxf(-15.f, x));
    float e = __expf(2.f * x);
    return (e - 1.f) / (e + 1.f);
}

// RED row stride 132 (2-way bank conflicts only)
#define RED(t, m, w, n)  red[(((t)*16 + (m))*132) + ((w)*16) + (n)]

// sum of the 8 per-wave partials for one gate column
__device__ __forceinline__ float sum8(const float* p) {
    return ((p[0] + p[16]) + (p[32] + p[48])) + ((p[64] + p[80]) + (p[96] + p[112]));
}

__global__ void __launch_bounds__(512, 1)
seq2seq_kernel(const float* __restrict__ enc_h, const float* __restrict__ enc_c,
               const float* __restrict__ emb_W,
               const float* __restrict__ dWih0, const float* __restrict__ dWhh0,
               const float* __restrict__ dbih0, const float* __restrict__ dbhh0,
               const float* __restrict__ dWih1, const float* __restrict__ dWhh1,
               const float* __restrict__ dbih1, const float* __restrict__ dbhh1,
               const float* __restrict__ eWih, const float* __restrict__ eWhh,
               const float* __restrict__ ebih, const float* __restrict__ ebhh,
               float* __restrict__ out, char* __restrict__ ws)
{
    const int tid  = threadIdx.x;
    const int wave = tid >> 6, lane = tid & 63;
    const int wg   = blockIdx.x;
    const int bg   = wg >> 7;          // batch group
    const int layer= (wg >> 6) & 1;    // decoder layer this WG owns
    const int g2   = wg & 63;          // u-slice index within (bg, layer)
    const int n16  = lane & 15;
    const int kq   = (lane >> 4) * 8;
    const int m    = n16;

    // spread flags: one per WG, 256B stride, in OUT's dec_h region (R5 lifetime ok)
    unsigned* flags  = (unsigned*)(out + 8388608);
    unsigned* myflag = flags + (size_t)wg * 64;

    f16* H1  = (f16*)(ws + WS_H1);    // [2 par][32][1024]
    f16* HE  = (f16*)(ws + WS_HE);    // [2 dir][2 par][32][512]
    f16* DEC = (f16*)(ws + WS_DEC);   // [256][32][1024]
    f16* Y0  = (f16*)(ws + WS_Y0);    // [256][32][1024]
    f16* H0R = Y0;                    // h0 ring [4][32][1024] (decoder phase only)

    __shared__ float red[64 * 132];
    __shared__ float cst[16][16];     // c-state for this WG's 16 units (dec + enc)
    __shared__ float bias_l[64];      // pre0 (L0) / bias1 (L1) / biasE (enc)

    unsigned cnt = 0;
    // wide barrier (P0 pairs, grid, encoder domains, terminal) -- R5 semantics
    auto barpollW = [&](int base, int width, unsigned tgt) {
        if (lane == 0)
            __hip_atomic_store(myflag, tgt, __ATOMIC_RELAXED, __HIP_MEMORY_SCOPE_AGENT);
        const unsigned* p0 = flags + (size_t)(base + (lane & (width - 1))) * 64;
        for (;;) {
            unsigned a = __hip_atomic_load(p0, __ATOMIC_RELAXED, __HIP_MEMORY_SCOPE_AGENT);
            if (width > 64) {
                unsigned b = __hip_atomic_load(p0 + 64 * 64, __ATOMIC_RELAXED, __HIP_MEMORY_SCOPE_AGENT);
                a = a < b ? a : b;
                if (width > 128) {
                    unsigned c2 = __hip_atomic_load(p0 + 128 * 64, __ATOMIC_RELAXED, __HIP_MEMORY_SCOPE_AGENT);
                    unsigned d2 = __hip_atomic_load(p0 + 192 * 64, __ATOMIC_RELAXED, __HIP_MEMORY_SCOPE_AGENT);
                    a = a < c2 ? a : c2;
                    a = a < d2 ? a : d2;
                }
            }
            if (__all((int)(a >= tgt))) break;
            __builtin_amdgcn_s_sleep(1);
        }
    };
    // decoder 64-wide dual-domain barrier: own set at tgt, other set at otgt
    auto barpoll2 = [&](int ownbase, int othbase, unsigned tgt, unsigned otgt) {
        if (lane == 0)
            __hip_atomic_store(myflag, tgt, __ATOMIC_RELAXED, __HIP_MEMORY_SCOPE_AGENT);
        const unsigned* p0 = flags + (size_t)(ownbase + lane) * 64;
        const unsigned* q0 = flags + (size_t)(othbase + lane) * 64;
        for (;;) {
            unsigned a = __hip_atomic_load(p0, __ATOMIC_RELAXED, __HIP_MEMORY_SCOPE_AGENT);
            unsigned b = __hip_atomic_load(q0, __ATOMIC_RELAXED, __HIP_MEMORY_SCOPE_AGENT);
            if (__all((int)((a >= tgt) && (b >= otgt)))) break;
            __builtin_amdgcn_s_sleep(1);
        }
    };

    // ---------------- P0: decoder weight fragments -> registers (U=16) ----------
    const int u0 = g2 * 16;
    hvec8 bW[4][8];
    {
        const int gate = n16 >> 2, uu = n16 & 3;
        if (layer == 0) {
#pragma unroll
            for (int t = 0; t < 4; ++t) {
                const int r = gate * 1024 + u0 + t * 4 + uu;
#pragma unroll
                for (int s = 0; s < 4; ++s)
                    bW[t][s] = ldb8(dWhh0 + (size_t)r * 1024 + wave * 128 + s * 32 + kq);
            }
        } else {
#pragma unroll
            for (int t = 0; t < 4; ++t) {
                const int r = gate * 1024 + u0 + t * 4 + uu;
#pragma unroll
                for (int s = 0; s < 8; ++s) {
                    const int k1 = wave * 256 + s * 32;
                    bW[t][s] = (k1 < 1024)
                        ? ldb8(dWih1 + (size_t)r * 1024 + k1 + kq)
                        : ldb8(dWhh1 + (size_t)r * 1024 + (k1 - 1024) + kq);
                }
            }
        }
    }
    // ---------------- P0: state init + pre0/bias ---------------------------------
    if (tid < 128) {
        const int j = tid >> 4, mm = tid & 15;
        const int b = bg * 16 + mm, u = u0 + 2 * j;
        const float* sc = enc_c + (size_t)(layer * 32 + b) * 1024 + u;
        const float* sh = enc_h + (size_t)(layer * 32 + b) * 1024 + u;
        cst[2 * j][mm]     = sc[0];
        cst[2 * j + 1][mm] = sc[1];
        if (layer == 0) st2(H0R + (size_t)(3 * 32 + b) * 1024 + u, sh[0], sh[1]); // slot 3
        else            st2(H1  + (size_t)(32 + b) * 1024 + u, sh[0], sh[1]);    // parity 1
    }
    if (tid < 64) {
        const int t = tid >> 4, nn = tid & 15;
        const int r = (nn >> 2) * 1024 + u0 + t * 4 + (nn & 3);
        if (layer == 0) {
            const float* x0 = emb_W + 512;     // emb_W[BOS=1]
            float s = dbih0[r] + dbhh0[r];
            const float* wr = dWih0 + (size_t)r * 512;
            for (int k = 0; k < 512; ++k) s += wr[k] * x0[k];
            bias_l[tid] = s;
        } else {
            bias_l[tid] = dbih1[r] + dbhh1[r];
        }
    }
    const int L0base = bg * 128, L1base = bg * 128 + 64;
    const int ownbase = layer ? L1base : L0base;
    const int othbase = layer ? L0base : L1base;
    __syncthreads();
    ++cnt;
    if (wave == 0) barpoll2(ownbase, othbase, cnt, cnt);   // P0: full 128-pair sync
    __syncthreads();

    // ---------------- decoder: 257 rounds, two decoupled domains -----------------
    for (int n = 0; n <= 256; ++n) {
        const int prd = (n + 1) & 1;   // h1 write parity
        const int pwr = n & 1;         // h1 read parity
        const bool act = layer ? (n >= 1) : (n < 256);
        fvec4 acc[4];
#pragma unroll
        for (int i = 0; i < 4; ++i) acc[i] = 0;
        if (act) {
            hvec8 af[8];
            if (layer == 0) {
                const f16* a0 = H0R + (size_t)((((n - 1) & 3)) * 32 + bg * 16 + m) * 1024
                              + wave * 128 + kq;
#pragma unroll
                for (int s = 0; s < 4; ++s) af[s] = lda8(a0 + s * 32);
                vm_wait();
#pragma unroll
                for (int s = 0; s < 4; ++s)
#pragma unroll
                    for (int t = 0; t < 4; ++t) acc[t] = mf(af[s], bW[t][s], acc[t]);
            } else {
                const f16* b0 = H0R + (size_t)((((n - 1) & 3)) * 32 + bg * 16 + m) * 1024;
                const f16* b1 = H1 + (size_t)(pwr * 32 + bg * 16 + m) * 1024;
#pragma unroll
                for (int s = 0; s < 8; ++s) {
                    const int k1 = wave * 256 + s * 32;
                    af[s] = lda8(k1 < 1024 ? b0 + k1 + kq : b1 + (k1 - 1024) + kq);
                }
                vm_wait();
#pragma unroll
                for (int s = 0; s < 8; ++s)
#pragma unroll
                    for (int t = 0; t < 4; ++t) acc[t] = mf(af[s], bW[t][s], acc[t]);
            }
        }
        {
            const int mg = lane >> 4;
#pragma unroll
            for (int t = 0; t < 4; ++t)
#pragma unroll
                for (int r2 = 0; r2 < 4; ++r2)
                    RED(t, mg * 4 + r2, wave, n16) = acc[t][r2];
        }
        __syncthreads();
        float s0 = 0.f, s1 = 0.f;            // deferred DEC payload (L1 only)
        int   sm2 = 0, sj = 0;
        if (tid >= 64 && tid < 192 && act) { // pointwise: waves 1-2, 16u x 16m
            const int q = tid - 64;
            const int j = q >> 4, m2 = q & 15;
            float hh[2];
#pragma unroll
            for (int e = 0; e < 2; ++e) {
                const int uu = 2 * j + e, tt = uu >> 2, ul = uu & 3;
                const float* p = &RED(tt, m2, 0, ul);
                const float gi = sum8(p)      + bias_l[tt * 16 + ul];
                const float gf = sum8(p + 4)  + bias_l[tt * 16 + 4 + ul];
                const float gg = sum8(p + 8)  + bias_l[tt * 16 + 8 + ul];
                const float go = sum8(p + 12) + bias_l[tt * 16 + 12 + ul];
                float c = cst[uu][m2];
                c = sigf(gf) * c + sigf(gi) * thf(gg);
                hh[e] = sigf(go) * thf(c);
                cst[uu][m2] = c;
            }
            const int b = bg * 16 + m2, u = u0 + 2 * j;
            if (layer == 0) {
                st2(H0R + (size_t)((n & 3) * 32 + b) * 1024 + u, hh[0], hh[1]);
            } else {
                st2(H1 + (size_t)(prd * 32 + b) * 1024 + u, hh[0], hh[1]);
                s0 = hh[0]; s1 = hh[1]; sm2 = m2; sj = j;   // DEC deferred
            }
        }
        __syncthreads();                     // drains h stores before flag
        ++cnt;
        if (wave == 0) {
            if (layer == 0) barpoll2(L0base, L1base, cnt, cnt < 2 ? 0u : cnt - 2);
            else            barpoll2(L1base, L0base, cnt, cnt);
        } else if (layer == 1 && tid >= 64 && tid < 192 && n >= 1) {
            st2(DEC + ((size_t)(n - 1) * 32 + bg * 16 + sm2) * 1024 + u0 + 2 * sj, s0, s1);
        }
        __syncthreads();
    }

    // one-time grid barrier: DEC (all bgs) visible; ring region may be recycled
    ++cnt;
    if (wave == 0) barpollW(0, 256, cnt);
    __syncthreads();
    if (wg >= 128) return;   // bg1-decoder WGs done (their flags never polled again)

    // ---------------- encoder: 2 layers x 256 ticks, U=16, 32 WGs/domain ---------
    const int bg2 = wg >> 6;
    const int dir = (wg >> 5) & 1;
    const int ge  = wg & 31;
    const int ue0 = ge * 16;
    const int dbase = bg2 * 64 + dir * 32;
    float fdh0 = 0.f, fdh1 = 0.f, fdc0 = 0.f, fdc1 = 0.f;  // final-state payload
    int   fdm2 = 0, fdj = 0;                               // (written post-terminal)
    for (int l = 0; l < 2; ++l) {
        hvec8 bE[4][6];
        {
            const int gate = n16 >> 2, uu = n16 & 3;
            const float* Wih = eWih + (size_t)(l * 2 + dir) * 2048 * 1024;
            const float* Whh = eWhh + (size_t)(l * 2 + dir) * 2048 * 512;
#pragma unroll
            for (int t = 0; t < 4; ++t) {
                const int r = gate * 512 + ue0 + t * 4 + uu;
#pragma unroll
                for (int s = 0; s < 6; ++s) {
                    const int kb = wave * 192 + s * 32;
                    bE[t][s] = (kb < 1024)
                        ? ldb8(Wih + (size_t)r * 1024 + kb + kq)
                        : ldb8(Whh + (size_t)r * 512 + (kb - 1024) + kq);
                }
            }
        }
        if (tid < 64) {
            const int t = tid >> 4, nn = tid & 15;
            const int r = (nn >> 2) * 512 + ue0 + t * 4 + (nn & 3);
            bias_l[tid] = ebih[(size_t)(l * 2 + dir) * 2048 + r]
                        + ebhh[(size_t)(l * 2 + dir) * 2048 + r];
        }
        if (tid < 128) {
            const int j = tid >> 4, mm = tid & 15;
            cst[2 * j][mm] = 0.f;
            cst[2 * j + 1][mm] = 0.f;
            st2(HE + (size_t)((dir * 2 + 1) * 32 + bg2 * 16 + mm) * 512 + ue0 + 2 * j, 0.f, 0.f);
        }
        __syncthreads();
        ++cnt;
        if (wave == 0) barpollW(dbase, 32, cnt);
        __syncthreads();
        const f16* yprev = (l == 0) ? DEC : Y0;
        // prologue: prefetch y fragments for tau=0
        hvec8 ypf[6];
        {
            const int t0 = dir ? 255 : 0;
            const int b = bg2 * 16 + n16;
#pragma unroll
            for (int s = 0; s < 6; ++s) {
                const int kb = wave * 192 + s * 32;
                if (kb < 1024)
                    ypf[s] = lda8(yprev + ((size_t)t0 * 32 + b) * 1024 + kb + kq);
            }
        }
        for (int tau = 0; tau < 256; ++tau) {
            const int t = dir ? (255 - tau) : tau;
            const int prd = (tau + 1) & 1, pwr = tau & 1;
            const int b = bg2 * 16 + n16;
            // recurrent HE loads (this tick's critical path)
            hvec8 hef[6];
#pragma unroll
            for (int s = 0; s < 6; ++s) {
                const int kb = wave * 192 + s * 32;
                if (kb >= 1024)
                    hef[s] = lda8(HE + (size_t)((dir * 2 + prd) * 32 + b) * 512 + (kb - 1024) + kq);
            }
            vm_wait();   // also covers last tick's y-prefetch
            fvec4 acc2[4];
#pragma unroll
            for (int i = 0; i < 4; ++i) acc2[i] = 0;
#pragma unroll
            for (int s = 0; s < 6; ++s) {
                const int kb = wave * 192 + s * 32;
                const hvec8 a = (kb < 1024) ? ypf[s] : hef[s];
                acc2[0] = mf(a, bE[0][s], acc2[0]);
                acc2[1] = mf(a, bE[1][s], acc2[1]);
                acc2[2] = mf(a, bE[2][s], acc2[2]);
                acc2[3] = mf(a, bE[3][s], acc2[3]);
            }
            // prefetch next tick's y fragments (schedule is known)
            if (tau < 255) {
                const int tn = dir ? (t - 1) : (t + 1);
#pragma unroll
                for (int s = 0; s < 6; ++s) {
                    const int kb = wave * 192 + s * 32;
                    if (kb < 1024)
                        ypf[s] = lda8(yprev + ((size_t)tn * 32 + b) * 1024 + kb + kq);
                }
            }
            const int mg = lane >> 4;
#pragma unroll
            for (int tt = 0; tt < 4; ++tt)
#pragma unroll
                for (int r2 = 0; r2 < 4; ++r2)
                    RED(tt, mg * 4 + r2, wave, n16) = acc2[tt][r2];
            __syncthreads();
            float dh0 = 0.f, dh1 = 0.f, dc0 = 0.f, dc1 = 0.f;  // deferred payload
            int   dm2 = 0, dj = 0;
            if (tid >= 64 && tid < 192) {                  // pointwise (waves 1-2)
                const int q = tid - 64;
                const int j = q >> 4, m2 = q & 15;
                float hh[2], cc[2];
#pragma unroll
                for (int e = 0; e < 2; ++e) {
                    const int uu = 2 * j + e, tt = uu >> 2, ul = uu & 3;
                    const float* p = &RED(tt, m2, 0, ul);
                    const float gi = sum8(p)      + bias_l[tt * 16 + ul];
                    const float gf = sum8(p + 4)  + bias_l[tt * 16 + 4 + ul];
                    const float gg = sum8(p + 8)  + bias_l[tt * 16 + 8 + ul];
                    const float go = sum8(p + 12) + bias_l[tt * 16 + 12 + ul];
                    float c = cst[uu][m2];
                    c = sigf(gf) * c + sigf(gi) * thf(gg);
                    hh[e] = sigf(go) * thf(c);
                    cc[e] = c;
                    cst[uu][m2] = c;
                }
                st2(HE + (size_t)((dir * 2 + pwr) * 32 + bg2 * 16 + m2) * 512 + ue0 + 2 * j,
                    hh[0], hh[1]);
                dh0 = hh[0]; dh1 = hh[1]; dc0 = cc[0]; dc1 = cc[1];
                dm2 = m2; dj = j;
            }
            __syncthreads();                               // drains HE (+ prev deferred)
            ++cnt;
            if (wave == 0) {
                if (!(l == 1 && tau == 255)) barpollW(dbase, 32, cnt);
            } else if (tid >= 64 && tid < 192) {
                const int b2 = bg2 * 16 + dm2, u = ue0 + 2 * dj;
                if (l == 0) {
                    st2(Y0 + ((size_t)t * 32 + b2) * 1024 + dir * 512 + u, dh0, dh1);
                } else {
                    float* o = out + ((size_t)b2 * 256 + t) * 1024 + dir * 512 + u;
                    o[0] = dh0; o[1] = dh1;
                    if (tau == 255) {   // final states: keep in REGISTERS until the
                        fdh0 = dh0; fdh1 = dh1;            // terminal barrier below
                        fdc0 = dc0; fdc1 = dc1;
                        fdm2 = dm2; fdj = dj;
                    }
                }
            }
            __syncthreads();
        }
        if (l == 0) {                                      // Y0 (both dirs) complete
            __syncthreads();                               // drains last deferred Y0
            ++cnt;
            if (wave == 0) barpollW(bg2 * 64, 64, cnt);
            __syncthreads();
        }
    }
    // terminal barrier: the LAST poll anywhere. After it, the flag region is dead
    // and may be overwritten by the final dec_h/dec_c stores.
    __syncthreads();
    ++cnt;
    if (wave == 0) barpollW(0, 128, cnt);
    __syncthreads();
    if (tid >= 64 && tid < 192) {
        const int b2 = bg2 * 16 + fdm2;
        const int col = dir * 512 + ue0 + 2 * fdj;
        float* oh = out + 8388608 + (size_t)b2 * 1024 + col;
        float* oc = out + 8454144 + (size_t)b2 * 1024 + col;
        oh[0] = fdh0; oh[1] = fdh1;
        oh[32768] = fdh0; oh[32769] = fdh1;
        oc[0] = fdc0; oc[1] = fdc1;
        oc[32768] = fdc0; oc[32769] = fdc1;
    }
}

extern "C" void kernel_launch(void* const* d_in, const int* in_sizes, int n_in,
                              void* d_out, int out_size, void* d_ws, size_t ws_size,
                              hipStream_t stream) {
    (void)in_sizes; (void)n_in; (void)out_size; (void)ws_size;
    const float* enc_h = (const float*)d_in[1];
    const float* enc_c = (const float*)d_in[2];
    const float* emb_W = (const float*)d_in[4];
    const float* dWih0 = (const float*)d_in[5];
    const float* dWhh0 = (const float*)d_in[6];
    const float* dbih0 = (const float*)d_in[7];
    const float* dbhh0 = (const float*)d_in[8];
    const float* dWih1 = (const float*)d_in[9];
    const float* dWhh1 = (const float*)d_in[10];
    const float* dbih1 = (const float*)d_in[11];
    const float* dbhh1 = (const float*)d_in[12];
    const float* eWih  = (const float*)d_in[13];
    const float* eWhh  = (const float*)d_in[14];
    const float* ebih  = (const float*)d_in[15];
    const float* ebhh  = (const float*)d_in[16];
    float* outp = (float*)d_out;
    char* ws = (char*)d_ws;

    // zero the spread flag region (lives in OUT's dec_h area; overwritten with real
    // dec_h values only after the kernel's terminal barrier)
    hipMemsetAsync((char*)d_out + 33554432, 0, 65536, stream);

    void* args[] = {&enc_h, &enc_c, &emb_W, &dWih0, &dWhh0, &dbih0, &dbhh0,
                    &dWih1, &dWhh1, &dbih1, &dbhh1, &eWih, &eWhh, &ebih, &ebhh,
                    &outp, &ws};
    hipLaunchCooperativeKernel((const void*)seq2seq_kernel, dim3(256), dim3(512),
                               args, 0, stream);
}